// Round 3
// baseline (1653.752 us; speedup 1.0000x reference)
//
#include <hip/hip_runtime.h>
#include <math.h>

// ---------------------------------------------------------------------------
// DeepECCNet: 3-layer gated graph conv + t-gate + MLP head. All fp32.
// CSR (by target) built once per launch; per layer: GEMM (W in LDS) ->
// gather-aggregate (no float atomics) with fused deg-normalize + ReLU.
// Self loops handled analytically (gate = sigmoid(w)).
// v3: handle n_in==14 (tuple inputs arrive as ONE concatenated buffer) and
//     n_in==20 (flattened); sentinel 900+n_in otherwise.
// ---------------------------------------------------------------------------

__device__ __forceinline__ float sigmoidf_(float v) { return 1.f / (1.f + expf(-v)); }

__global__ void sentinel_kernel(float* __restrict__ out, int n, float val) {
  int i = blockIdx.x * 256 + threadIdx.x;
  if (i < n) out[i] = val;
}

__global__ void zero_kernel(int* __restrict__ p, int n) {
  int i = blockIdx.x * 256 + threadIdx.x;
  if (i < n) p[i] = 0;
}

// ---- edge-index dtype hedge: int64 has all-zero hi (odd) words -------------
__global__ void detect_kernel(const int* __restrict__ ei, int* __restrict__ flag) {
  if (threadIdx.x == 0 && blockIdx.x == 0) {
    int all0 = 1;
    for (int i = 1; i < 512; i += 2) {
      if (ei[i] != 0) { all0 = 0; break; }
    }
    *flag = all0;
  }
}

__global__ void cvt_kernel(const int* __restrict__ ei, int E, const int* __restrict__ flag,
                           int* __restrict__ src32, int* __restrict__ tgt32) {
  int e = blockIdx.x * blockDim.x + threadIdx.x;
  if (e >= E) return;
  if (*flag) {
    const long long* e64 = (const long long*)ei;
    src32[e] = (int)e64[e];
    tgt32[e] = (int)e64[(size_t)E + e];
  } else {
    src32[e] = ei[e];
    tgt32[e] = ei[(size_t)E + e];
  }
}

// ---- CSR build (all index uses bounds-guarded) -----------------------------
__global__ void count_kernel(const int* __restrict__ tgt, int E, int n,
                             int* __restrict__ counts) {
  int e = blockIdx.x * blockDim.x + threadIdx.x;
  if (e < E) {
    unsigned t = (unsigned)tgt[e];
    if (t < (unsigned)n) atomicAdd(&counts[t], 1);
  }
}

__global__ void scan1_kernel(const int* __restrict__ counts, int n,
                             int* __restrict__ starts, int* __restrict__ bsums) {
  __shared__ int tmp[256];
  int i = blockIdx.x * 256 + threadIdx.x;
  int v = (i < n) ? counts[i] : 0;
  tmp[threadIdx.x] = v;
  __syncthreads();
  for (int off = 1; off < 256; off <<= 1) {
    int t = (threadIdx.x >= (unsigned)off) ? tmp[threadIdx.x - off] : 0;
    __syncthreads();
    tmp[threadIdx.x] += t;
    __syncthreads();
  }
  if (i < n) starts[i] = tmp[threadIdx.x] - v;  // exclusive
  if (threadIdx.x == 255) bsums[blockIdx.x] = tmp[255];
}

__global__ void scan2_kernel(int* __restrict__ bsums, int nb) {
  __shared__ int tmp[512];
  int v = (threadIdx.x < (unsigned)nb) ? bsums[threadIdx.x] : 0;
  tmp[threadIdx.x] = v;
  __syncthreads();
  for (int off = 1; off < 512; off <<= 1) {
    int t = (threadIdx.x >= (unsigned)off) ? tmp[threadIdx.x - off] : 0;
    __syncthreads();
    tmp[threadIdx.x] += t;
    __syncthreads();
  }
  if (threadIdx.x < (unsigned)nb) bsums[threadIdx.x] = tmp[threadIdx.x] - v;  // exclusive
}

__global__ void scan3_kernel(int* __restrict__ starts, const int* __restrict__ bsums,
                             int n, int* __restrict__ cursor) {
  int i = blockIdx.x * 256 + threadIdx.x;
  if (i < n) {
    int s = starts[i] + bsums[blockIdx.x];
    starts[i] = s;
    cursor[i] = s;
  }
}

__global__ void fill_kernel(const int* __restrict__ src, const int* __restrict__ tgt,
                            const float* __restrict__ ea, int E, int n,
                            int* __restrict__ cursor,
                            int* __restrict__ csr_src, float* __restrict__ csr_ea) {
  int e = blockIdx.x * blockDim.x + threadIdx.x;
  if (e < E) {
    unsigned t = (unsigned)tgt[e];
    if (t >= (unsigned)n) return;
    int slot = atomicAdd(&cursor[t], 1);
    if ((unsigned)slot < (unsigned)E) {
      csr_src[slot] = src[e];
      csr_ea[slot] = ea[e];
    }
  }
}

// per-layer gate precompute (keeps expf out of the gather hot loop)
__global__ void gates_kernel(const float* __restrict__ csr_ea, const float* __restrict__ wp,
                             float* __restrict__ g, int E) {
  int e = blockIdx.x * blockDim.x + threadIdx.x;
  if (e < E) g[e] = sigmoidf_(csr_ea[e] * wp[0]);
}

// ---- h0 = x[:, 1:] ---------------------------------------------------------
__global__ void slice_kernel(const float* __restrict__ x, float* __restrict__ h, int n) {
  int idx = blockIdx.x * blockDim.x + threadIdx.x;
  if (idx < n * 128) {
    int node = idx >> 7;
    int k = idx & 127;
    h[idx] = x[(size_t)node * 129 + 1 + k];
  }
}

// ---- t path: t = sigmoid(relu(x@t1W+t1b)@t2W+t2b) — one wave per node ------
__global__ __launch_bounds__(256) void tnet_kernel(const float* __restrict__ x,
    const float* __restrict__ t1W, const float* __restrict__ t1b,
    const float* __restrict__ t2W, const float* __restrict__ t2b,
    float* __restrict__ t, int n) {
  int wv = threadIdx.x >> 6, lane = threadIdx.x & 63;
  int node = blockIdx.x * 4 + wv;
  if (node >= n) return;
  const float* xr = x + (size_t)node * 129;
  float acc = t1b[lane];
  for (int k = 0; k < 129; k++) acc += xr[k] * t1W[k * 64 + lane];
  acc = fmaxf(acc, 0.f);
  float p = acc * t2W[lane];
  for (int off = 32; off; off >>= 1) p += __shfl_down(p, off);
  if (lane == 0) t[node] = sigmoidf_(p + t2b[0]);
}

// ---- GEMM: ht = h @ W + b  (h: n x 128, W: 128x128 staged in LDS) ----------
__global__ __launch_bounds__(256) void gemm128_kernel(const float* __restrict__ h,
    const float* __restrict__ Wg, const float* __restrict__ b,
    float* __restrict__ out, int n) {
  __shared__ float sW[16384];  // 64 KB
  {
    float4* d = (float4*)sW;
    const float4* s = (const float4*)Wg;
    for (int i = threadIdx.x; i < 4096; i += 256) d[i] = s[i];
  }
  __syncthreads();
  int wv = threadIdx.x >> 6, lane = threadIdx.x & 63;
  int base = (blockIdx.x * 4 + wv) * 16;
  float b0 = b[lane], b1 = b[lane + 64];
  for (int g = 0; g < 4; g++) {
    int n0 = base + g * 4;
    if (n0 >= n) break;
    int i1 = min(n0 + 1, n - 1), i2 = min(n0 + 2, n - 1), i3 = min(n0 + 3, n - 1);
    const float4* h0 = (const float4*)(h + (size_t)n0 * 128);
    const float4* h1 = (const float4*)(h + (size_t)i1 * 128);
    const float4* h2 = (const float4*)(h + (size_t)i2 * 128);
    const float4* h3 = (const float4*)(h + (size_t)i3 * 128);
    float a00 = b0, a01 = b1, a10 = b0, a11 = b1;
    float a20 = b0, a21 = b1, a30 = b0, a31 = b1;
    for (int k4 = 0; k4 < 32; k4++) {
      float4 v0 = h0[k4], v1 = h1[k4], v2 = h2[k4], v3 = h3[k4];
      const float* e0 = (const float*)&v0;
      const float* e1 = (const float*)&v1;
      const float* e2 = (const float*)&v2;
      const float* e3 = (const float*)&v3;
#pragma unroll
      for (int kk = 0; kk < 4; kk++) {
        float w0 = sW[(k4 * 4 + kk) * 128 + lane];
        float w1 = sW[(k4 * 4 + kk) * 128 + 64 + lane];
        a00 += e0[kk] * w0; a01 += e0[kk] * w1;
        a10 += e1[kk] * w0; a11 += e1[kk] * w1;
        a20 += e2[kk] * w0; a21 += e2[kk] * w1;
        a30 += e3[kk] * w0; a31 += e3[kk] * w1;
      }
    }
    size_t o0 = (size_t)n0 * 128;
    out[o0 + lane] = a00;            out[o0 + 64 + lane] = a01;
    if (n0 + 1 < n) { out[o0 + 128 + lane] = a10; out[o0 + 192 + lane] = a11; }
    if (n0 + 2 < n) { out[o0 + 256 + lane] = a20; out[o0 + 320 + lane] = a21; }
    if (n0 + 3 < n) { out[o0 + 384 + lane] = a30; out[o0 + 448 + lane] = a31; }
  }
}

// ---- aggregation: h' = relu( (sig(w)*ht[v] + sum_e g_e*ht[src_e]) / deg ) --
__global__ __launch_bounds__(256) void agg_kernel(const float* __restrict__ ht,
    const int* __restrict__ csr_src, const float* __restrict__ gates,
    const int* __restrict__ starts, const int* __restrict__ counts,
    const float* __restrict__ wp, float* __restrict__ hout, int n) {
  int wv = threadIdx.x >> 6, lane = threadIdx.x & 63;
  int node = blockIdx.x * 4 + wv;
  if (node >= n) return;
  int s = starts[node], c = counts[node];
  float gs = sigmoidf_(wp[0]);
  float2 v0 = ((const float2*)(ht + (size_t)node * 128))[lane];
  float ax = gs * v0.x, ay = gs * v0.y;
  for (int j = 0; j < c; j++) {
    unsigned sn = (unsigned)csr_src[s + j];
    float g = gates[s + j];
    if (sn < (unsigned)n) {
      float2 v = ((const float2*)(ht + (size_t)sn * 128))[lane];
      ax += g * v.x;
      ay += g * v.y;
    }
  }
  float inv = 1.f / (float)(c + 1);
  ax = fmaxf(ax * inv, 0.f);
  ay = fmaxf(ay * inv, 0.f);
  ((float2*)(hout + (size_t)node * 128))[lane] = make_float2(ax, ay);
}

// ---- head: out = sigmoid(relu([h,t]@l1W+l1b)@l2W+l2b) — one wave per node --
__global__ __launch_bounds__(256) void mlp_kernel(const float* __restrict__ h,
    const float* __restrict__ t, const float* __restrict__ l1W,
    const float* __restrict__ l1b, const float* __restrict__ l2W,
    const float* __restrict__ l2b, float* __restrict__ out, int n) {
  int wv = threadIdx.x >> 6, lane = threadIdx.x & 63;
  int node = blockIdx.x * 4 + wv;
  if (node >= n) return;
  const float* hr = h + (size_t)node * 128;
  float acc = l1b[lane];
  for (int k = 0; k < 128; k++) acc += hr[k] * l1W[k * 64 + lane];
  acc += t[node] * l1W[128 * 64 + lane];
  acc = fmaxf(acc, 0.f);
  float p = acc * l2W[lane];
  for (int off = 32; off; off >>= 1) p += __shfl_down(p, off);
  if (lane == 0) out[node] = sigmoidf_(p + l2b[0]);
}

// ---------------------------------------------------------------------------
extern "C" void kernel_launch(void* const* d_in, const int* in_sizes, int n_in,
                              void* d_out, int out_size, void* d_ws, size_t ws_size,
                              hipStream_t stream) {
  int ob = (out_size + 255) / 256;

  const float *x, *ea, *l1W, *l1b, *l2W, *l2b, *t1W, *t1b, *t2W, *t2b;
  const float *convW[3], *convb[3], *edgew[3];
  const int* ei;

  if (n_in == 20) {          // tuples flattened to separate entries
    x = (const float*)d_in[0]; ei = (const int*)d_in[1]; ea = (const float*)d_in[2];
    for (int l = 0; l < 3; l++) {
      convW[l] = (const float*)d_in[3 + l];
      convb[l] = (const float*)d_in[6 + l];
      edgew[l] = (const float*)d_in[9 + l];
    }
    l1W = (const float*)d_in[12]; l1b = (const float*)d_in[13];
    l2W = (const float*)d_in[14]; l2b = (const float*)d_in[15];
    t1W = (const float*)d_in[16]; t1b = (const float*)d_in[17];
    t2W = (const float*)d_in[18]; t2b = (const float*)d_in[19];
  } else if (n_in == 14) {   // each tuple is ONE concatenated buffer
    x = (const float*)d_in[0]; ei = (const int*)d_in[1]; ea = (const float*)d_in[2];
    const float* cw = (const float*)d_in[3];   // 3 x (128*128)
    const float* cb = (const float*)d_in[4];   // 3 x 128
    const float* ew = (const float*)d_in[5];   // 3 x 1
    for (int l = 0; l < 3; l++) {
      convW[l] = cw + (size_t)l * 128 * 128;
      convb[l] = cb + (size_t)l * 128;
      edgew[l] = ew + l;
    }
    l1W = (const float*)d_in[6];  l1b = (const float*)d_in[7];
    l2W = (const float*)d_in[8];  l2b = (const float*)d_in[9];
    t1W = (const float*)d_in[10]; t1b = (const float*)d_in[11];
    t2W = (const float*)d_in[12]; t2b = (const float*)d_in[13];
  } else {                   // unknown layout -> encode n_in in sentinel
    sentinel_kernel<<<ob, 256, 0, stream>>>((float*)d_out, out_size,
                                            900.0f + (float)n_in);
    return;
  }

  int n = in_sizes[0] / 129;   // 100000
  int E = in_sizes[2];         // 1600000 (edge_attr element count)

  char* ws = (char*)d_ws;
  size_t off = 0;
  auto take = [&](size_t bytes) -> void* {
    void* p = ws + off;
    off = (off + bytes + 255) & ~(size_t)255;
    return p;
  };
  int*   flag    = (int*)take(256);
  int*   counts  = (int*)take((size_t)n * 4);
  int*   starts  = (int*)take((size_t)n * 4);
  int*   cursor  = (int*)take((size_t)n * 4);
  int*   bsums   = (int*)take(512 * 4);
  float* tbuf    = (float*)take((size_t)n * 4);
  int*   csr_src = (int*)take((size_t)E * 4);
  float* csr_ea  = (float*)take((size_t)E * 4);
  float* gbuf    = (float*)take((size_t)E * 4);
  float* hA      = (float*)take((size_t)n * 128 * 4);
  float* htb     = (float*)take((size_t)n * 128 * 4);
  // transient src32/tgt32 alias into htb (dead before first GEMM writes htb)
  int* src32 = (int*)htb;
  int* tgt32 = src32 + E;

  if (off > ws_size) {  // workspace too small -> sentinel encodes ws MB
    sentinel_kernel<<<ob, 256, 0, stream>>>((float*)d_out, out_size,
                                            1000.0f + (float)(ws_size >> 20));
    return;
  }

  int eb = (E + 255) / 256;
  int nb = (n + 255) / 256;  // 391 <= 512 (scan2 capacity)

  detect_kernel<<<1, 64, 0, stream>>>(ei, flag);
  cvt_kernel<<<eb, 256, 0, stream>>>(ei, E, flag, src32, tgt32);

  zero_kernel<<<nb, 256, 0, stream>>>(counts, n);
  count_kernel<<<eb, 256, 0, stream>>>(tgt32, E, n, counts);
  scan1_kernel<<<nb, 256, 0, stream>>>(counts, n, starts, bsums);
  scan2_kernel<<<1, 512, 0, stream>>>(bsums, nb);
  scan3_kernel<<<nb, 256, 0, stream>>>(starts, bsums, n, cursor);
  fill_kernel<<<eb, 256, 0, stream>>>(src32, tgt32, ea, E, n, cursor, csr_src, csr_ea);

  int sb = (int)(((size_t)n * 128 + 255) / 256);
  slice_kernel<<<sb, 256, 0, stream>>>(x, hA, n);
  tnet_kernel<<<(n + 3) / 4, 256, 0, stream>>>(x, t1W, t1b, t2W, t2b, tbuf, n);

  for (int l = 0; l < 3; l++) {
    gemm128_kernel<<<(n + 63) / 64, 256, 0, stream>>>(hA, convW[l], convb[l], htb, n);
    gates_kernel<<<eb, 256, 0, stream>>>(csr_ea, edgew[l], gbuf, E);
    agg_kernel<<<(n + 3) / 4, 256, 0, stream>>>(htb, csr_src, gbuf, starts, counts,
                                                edgew[l], hA, n);
  }

  mlp_kernel<<<(n + 3) / 4, 256, 0, stream>>>(hA, tbuf, l1W, l1b, l2W, l2b,
                                              (float*)d_out, n);
}

// Round 4
// 1459.569 us; speedup vs baseline: 1.1330x; 1.1330x over previous
//
#include <hip/hip_runtime.h>
#include <math.h>

// ---------------------------------------------------------------------------
// DeepECCNet: 3-layer gated graph conv + t-gate + MLP head. All fp32.
// CSR (by target) built once per launch; per layer: GEMM (W in LDS) ->
// gather-aggregate (no float atomics) with fused deg-normalize + ReLU.
// v4: tnet/mlp rebuilt GEMM-style (LDS weights, float4 row loads, 8-node ILP
//     groups) — v3's scalar k-loops were latency-bound at 226 us each.
// ---------------------------------------------------------------------------

__device__ __forceinline__ float sigmoidf_(float v) { return 1.f / (1.f + expf(-v)); }

__global__ void sentinel_kernel(float* __restrict__ out, int n, float val) {
  int i = blockIdx.x * 256 + threadIdx.x;
  if (i < n) out[i] = val;
}

__global__ void zero_kernel(int* __restrict__ p, int n) {
  int i = blockIdx.x * 256 + threadIdx.x;
  if (i < n) p[i] = 0;
}

// ---- edge-index dtype hedge: int64 has all-zero hi (odd) words -------------
__global__ void detect_kernel(const int* __restrict__ ei, int* __restrict__ flag) {
  if (threadIdx.x == 0 && blockIdx.x == 0) {
    int all0 = 1;
    for (int i = 1; i < 512; i += 2) {
      if (ei[i] != 0) { all0 = 0; break; }
    }
    *flag = all0;
  }
}

__global__ void cvt_kernel(const int* __restrict__ ei, int E, const int* __restrict__ flag,
                           int* __restrict__ src32, int* __restrict__ tgt32) {
  int e = blockIdx.x * blockDim.x + threadIdx.x;
  if (e >= E) return;
  if (*flag) {
    const long long* e64 = (const long long*)ei;
    src32[e] = (int)e64[e];
    tgt32[e] = (int)e64[(size_t)E + e];
  } else {
    src32[e] = ei[e];
    tgt32[e] = ei[(size_t)E + e];
  }
}

// ---- CSR build (all index uses bounds-guarded) -----------------------------
__global__ void count_kernel(const int* __restrict__ tgt, int E, int n,
                             int* __restrict__ counts) {
  int e = blockIdx.x * blockDim.x + threadIdx.x;
  if (e < E) {
    unsigned t = (unsigned)tgt[e];
    if (t < (unsigned)n) atomicAdd(&counts[t], 1);
  }
}

__global__ void scan1_kernel(const int* __restrict__ counts, int n,
                             int* __restrict__ starts, int* __restrict__ bsums) {
  __shared__ int tmp[256];
  int i = blockIdx.x * 256 + threadIdx.x;
  int v = (i < n) ? counts[i] : 0;
  tmp[threadIdx.x] = v;
  __syncthreads();
  for (int off = 1; off < 256; off <<= 1) {
    int t = (threadIdx.x >= (unsigned)off) ? tmp[threadIdx.x - off] : 0;
    __syncthreads();
    tmp[threadIdx.x] += t;
    __syncthreads();
  }
  if (i < n) starts[i] = tmp[threadIdx.x] - v;  // exclusive
  if (threadIdx.x == 255) bsums[blockIdx.x] = tmp[255];
}

__global__ void scan2_kernel(int* __restrict__ bsums, int nb) {
  __shared__ int tmp[512];
  int v = (threadIdx.x < (unsigned)nb) ? bsums[threadIdx.x] : 0;
  tmp[threadIdx.x] = v;
  __syncthreads();
  for (int off = 1; off < 512; off <<= 1) {
    int t = (threadIdx.x >= (unsigned)off) ? tmp[threadIdx.x - off] : 0;
    __syncthreads();
    tmp[threadIdx.x] += t;
    __syncthreads();
  }
  if (threadIdx.x < (unsigned)nb) bsums[threadIdx.x] = tmp[threadIdx.x] - v;  // exclusive
}

__global__ void scan3_kernel(int* __restrict__ starts, const int* __restrict__ bsums,
                             int n, int* __restrict__ cursor) {
  int i = blockIdx.x * 256 + threadIdx.x;
  if (i < n) {
    int s = starts[i] + bsums[blockIdx.x];
    starts[i] = s;
    cursor[i] = s;
  }
}

__global__ void fill_kernel(const int* __restrict__ src, const int* __restrict__ tgt,
                            const float* __restrict__ ea, int E, int n,
                            int* __restrict__ cursor,
                            int* __restrict__ csr_src, float* __restrict__ csr_ea) {
  int e = blockIdx.x * blockDim.x + threadIdx.x;
  if (e < E) {
    unsigned t = (unsigned)tgt[e];
    if (t >= (unsigned)n) return;
    int slot = atomicAdd(&cursor[t], 1);
    if ((unsigned)slot < (unsigned)E) {
      csr_src[slot] = src[e];
      csr_ea[slot] = ea[e];
    }
  }
}

// per-layer gate precompute (keeps expf out of the gather hot loop)
__global__ void gates_kernel(const float* __restrict__ csr_ea, const float* __restrict__ wp,
                             float* __restrict__ g, int E) {
  int e = blockIdx.x * blockDim.x + threadIdx.x;
  if (e < E) g[e] = sigmoidf_(csr_ea[e] * wp[0]);
}

// ---- h0 = x[:, 1:]; x0 = x[:, 0] ------------------------------------------
__global__ void slice_kernel(const float* __restrict__ x, float* __restrict__ h,
                             float* __restrict__ x0, int n) {
  int idx = blockIdx.x * blockDim.x + threadIdx.x;
  if (idx < n * 128) {
    int node = idx >> 7;
    int k = idx & 127;
    h[idx] = x[(size_t)node * 129 + 1 + k];
  }
  if (idx < n) x0[idx] = x[(size_t)idx * 129];
}

// ---- t path (GEMM-style): t = sigmoid(relu([x0,hA]@t1W+t1b)@t2W+t2b) -------
// LDS weights; 16 nodes/wave in two 8-node ILP groups; float4 row loads.
__global__ __launch_bounds__(256) void tnet2_kernel(const float* __restrict__ hA,
    const float* __restrict__ x0, const float* __restrict__ t1W,
    const float* __restrict__ t1b, const float* __restrict__ t2W,
    const float* __restrict__ t2b, float* __restrict__ t, int n) {
  __shared__ float sW[128 * 64];  // t1W rows k=1..128: sW[(k-1)*64+o]
  __shared__ float sW0[64], sB[64], sT2[64];
  for (int i = threadIdx.x; i < 128 * 64; i += 256) {
    int k = i >> 6, o = i & 63;
    sW[i] = t1W[(k + 1) * 64 + o];
  }
  if (threadIdx.x < 64) {
    sW0[threadIdx.x] = t1W[threadIdx.x];
    sB[threadIdx.x] = t1b[threadIdx.x];
    sT2[threadIdx.x] = t2W[threadIdx.x];
  }
  __syncthreads();
  int wv = threadIdx.x >> 6, lane = threadIdx.x & 63;
  int base = (blockIdx.x * 4 + wv) * 16;
  if (base >= n) return;
  float w0 = sW0[lane], bb = sB[lane], t2 = sT2[lane];
  float t2b0 = t2b[0];
  for (int g = 0; g < 2; g++) {
    int n0 = base + g * 8;
    if (n0 >= n) break;
    const float4* hp[8];
    float acc[8];
#pragma unroll
    for (int i = 0; i < 8; i++) {
      int id = min(n0 + i, n - 1);
      hp[i] = (const float4*)(hA + (size_t)id * 128);
      acc[i] = bb + x0[id] * w0;
    }
    for (int k4 = 0; k4 < 32; k4++) {
      float4 v[8];
#pragma unroll
      for (int i = 0; i < 8; i++) v[i] = hp[i][k4];
#pragma unroll
      for (int kk = 0; kk < 4; kk++) {
        float w = sW[(k4 * 4 + kk) * 64 + lane];
#pragma unroll
        for (int i = 0; i < 8; i++) acc[i] += ((const float*)&v[i])[kk] * w;
      }
    }
#pragma unroll
    for (int i = 0; i < 8; i++) {
      float p = fmaxf(acc[i], 0.f) * t2;
      for (int off2 = 32; off2; off2 >>= 1) p += __shfl_down(p, off2);
      if (lane == 0 && n0 + i < n) t[n0 + i] = sigmoidf_(p + t2b0);
    }
  }
}

// ---- head (GEMM-style): out = sigmoid(relu([h,t]@l1W+l1b)@l2W+l2b) ---------
__global__ __launch_bounds__(256) void mlp2_kernel(const float* __restrict__ h,
    const float* __restrict__ t, const float* __restrict__ l1W,
    const float* __restrict__ l1b, const float* __restrict__ l2W,
    const float* __restrict__ l2b, float* __restrict__ out, int n) {
  __shared__ float sW[128 * 64];  // l1W rows k=0..127
  __shared__ float sWt[64], sB[64], sL2[64];
  for (int i = threadIdx.x; i < 128 * 64; i += 256) sW[i] = l1W[i];
  if (threadIdx.x < 64) {
    sWt[threadIdx.x] = l1W[128 * 64 + threadIdx.x];
    sB[threadIdx.x] = l1b[threadIdx.x];
    sL2[threadIdx.x] = l2W[threadIdx.x];
  }
  __syncthreads();
  int wv = threadIdx.x >> 6, lane = threadIdx.x & 63;
  int base = (blockIdx.x * 4 + wv) * 16;
  if (base >= n) return;
  float wt = sWt[lane], bb = sB[lane], l2 = sL2[lane];
  float l2b0 = l2b[0];
  for (int g = 0; g < 2; g++) {
    int n0 = base + g * 8;
    if (n0 >= n) break;
    const float4* hp[8];
    float acc[8];
#pragma unroll
    for (int i = 0; i < 8; i++) {
      int id = min(n0 + i, n - 1);
      hp[i] = (const float4*)(h + (size_t)id * 128);
      acc[i] = bb + t[id] * wt;
    }
    for (int k4 = 0; k4 < 32; k4++) {
      float4 v[8];
#pragma unroll
      for (int i = 0; i < 8; i++) v[i] = hp[i][k4];
#pragma unroll
      for (int kk = 0; kk < 4; kk++) {
        float w = sW[(k4 * 4 + kk) * 64 + lane];
#pragma unroll
        for (int i = 0; i < 8; i++) acc[i] += ((const float*)&v[i])[kk] * w;
      }
    }
#pragma unroll
    for (int i = 0; i < 8; i++) {
      float p = fmaxf(acc[i], 0.f) * l2;
      for (int off2 = 32; off2; off2 >>= 1) p += __shfl_down(p, off2);
      if (lane == 0 && n0 + i < n) out[n0 + i] = sigmoidf_(p + l2b0);
    }
  }
}

// ---- GEMM: ht = h @ W + b  (h: n x 128, W: 128x128 staged in LDS) ----------
__global__ __launch_bounds__(256) void gemm128_kernel(const float* __restrict__ h,
    const float* __restrict__ Wg, const float* __restrict__ b,
    float* __restrict__ out, int n) {
  __shared__ float sW[16384];  // 64 KB
  {
    float4* d = (float4*)sW;
    const float4* s = (const float4*)Wg;
    for (int i = threadIdx.x; i < 4096; i += 256) d[i] = s[i];
  }
  __syncthreads();
  int wv = threadIdx.x >> 6, lane = threadIdx.x & 63;
  int base = (blockIdx.x * 4 + wv) * 16;
  float b0 = b[lane], b1 = b[lane + 64];
  for (int g = 0; g < 4; g++) {
    int n0 = base + g * 4;
    if (n0 >= n) break;
    int i1 = min(n0 + 1, n - 1), i2 = min(n0 + 2, n - 1), i3 = min(n0 + 3, n - 1);
    const float4* h0 = (const float4*)(h + (size_t)n0 * 128);
    const float4* h1 = (const float4*)(h + (size_t)i1 * 128);
    const float4* h2 = (const float4*)(h + (size_t)i2 * 128);
    const float4* h3 = (const float4*)(h + (size_t)i3 * 128);
    float a00 = b0, a01 = b1, a10 = b0, a11 = b1;
    float a20 = b0, a21 = b1, a30 = b0, a31 = b1;
    for (int k4 = 0; k4 < 32; k4++) {
      float4 v0 = h0[k4], v1 = h1[k4], v2 = h2[k4], v3 = h3[k4];
      const float* e0 = (const float*)&v0;
      const float* e1 = (const float*)&v1;
      const float* e2 = (const float*)&v2;
      const float* e3 = (const float*)&v3;
#pragma unroll
      for (int kk = 0; kk < 4; kk++) {
        float w0 = sW[(k4 * 4 + kk) * 128 + lane];
        float w1 = sW[(k4 * 4 + kk) * 128 + 64 + lane];
        a00 += e0[kk] * w0; a01 += e0[kk] * w1;
        a10 += e1[kk] * w0; a11 += e1[kk] * w1;
        a20 += e2[kk] * w0; a21 += e2[kk] * w1;
        a30 += e3[kk] * w0; a31 += e3[kk] * w1;
      }
    }
    size_t o0 = (size_t)n0 * 128;
    out[o0 + lane] = a00;            out[o0 + 64 + lane] = a01;
    if (n0 + 1 < n) { out[o0 + 128 + lane] = a10; out[o0 + 192 + lane] = a11; }
    if (n0 + 2 < n) { out[o0 + 256 + lane] = a20; out[o0 + 320 + lane] = a21; }
    if (n0 + 3 < n) { out[o0 + 384 + lane] = a30; out[o0 + 448 + lane] = a31; }
  }
}

// ---- aggregation: h' = relu( (sig(w)*ht[v] + sum_e g_e*ht[src_e]) / deg ) --
__global__ __launch_bounds__(256) void agg_kernel(const float* __restrict__ ht,
    const int* __restrict__ csr_src, const float* __restrict__ gates,
    const int* __restrict__ starts, const int* __restrict__ counts,
    const float* __restrict__ wp, float* __restrict__ hout, int n) {
  int wv = threadIdx.x >> 6, lane = threadIdx.x & 63;
  int node = blockIdx.x * 4 + wv;
  if (node >= n) return;
  int s = starts[node], c = counts[node];
  float gs = sigmoidf_(wp[0]);
  float2 v0 = ((const float2*)(ht + (size_t)node * 128))[lane];
  float ax = gs * v0.x, ay = gs * v0.y;
  for (int j = 0; j < c; j++) {
    unsigned sn = (unsigned)csr_src[s + j];
    float g = gates[s + j];
    if (sn < (unsigned)n) {
      float2 v = ((const float2*)(ht + (size_t)sn * 128))[lane];
      ax += g * v.x;
      ay += g * v.y;
    }
  }
  float inv = 1.f / (float)(c + 1);
  ax = fmaxf(ax * inv, 0.f);
  ay = fmaxf(ay * inv, 0.f);
  ((float2*)(hout + (size_t)node * 128))[lane] = make_float2(ax, ay);
}

// ---------------------------------------------------------------------------
extern "C" void kernel_launch(void* const* d_in, const int* in_sizes, int n_in,
                              void* d_out, int out_size, void* d_ws, size_t ws_size,
                              hipStream_t stream) {
  int ob = (out_size + 255) / 256;

  const float *x, *ea, *l1W, *l1b, *l2W, *l2b, *t1W, *t1b, *t2W, *t2b;
  const float *convW[3], *convb[3], *edgew[3];
  const int* ei;

  if (n_in == 20) {          // tuples flattened to separate entries
    x = (const float*)d_in[0]; ei = (const int*)d_in[1]; ea = (const float*)d_in[2];
    for (int l = 0; l < 3; l++) {
      convW[l] = (const float*)d_in[3 + l];
      convb[l] = (const float*)d_in[6 + l];
      edgew[l] = (const float*)d_in[9 + l];
    }
    l1W = (const float*)d_in[12]; l1b = (const float*)d_in[13];
    l2W = (const float*)d_in[14]; l2b = (const float*)d_in[15];
    t1W = (const float*)d_in[16]; t1b = (const float*)d_in[17];
    t2W = (const float*)d_in[18]; t2b = (const float*)d_in[19];
  } else if (n_in == 14) {   // each tuple is ONE concatenated buffer
    x = (const float*)d_in[0]; ei = (const int*)d_in[1]; ea = (const float*)d_in[2];
    const float* cw = (const float*)d_in[3];   // 3 x (128*128)
    const float* cb = (const float*)d_in[4];   // 3 x 128
    const float* ew = (const float*)d_in[5];   // 3 x 1
    for (int l = 0; l < 3; l++) {
      convW[l] = cw + (size_t)l * 128 * 128;
      convb[l] = cb + (size_t)l * 128;
      edgew[l] = ew + l;
    }
    l1W = (const float*)d_in[6];  l1b = (const float*)d_in[7];
    l2W = (const float*)d_in[8];  l2b = (const float*)d_in[9];
    t1W = (const float*)d_in[10]; t1b = (const float*)d_in[11];
    t2W = (const float*)d_in[12]; t2b = (const float*)d_in[13];
  } else {
    sentinel_kernel<<<ob, 256, 0, stream>>>((float*)d_out, out_size,
                                            900.0f + (float)n_in);
    return;
  }

  int n = in_sizes[0] / 129;   // 100000
  int E = in_sizes[2];         // 1600000 (edge_attr element count)

  char* ws = (char*)d_ws;
  size_t off = 0;
  auto take = [&](size_t bytes) -> void* {
    void* p = ws + off;
    off = (off + bytes + 255) & ~(size_t)255;
    return p;
  };
  int*   flag    = (int*)take(256);
  int*   counts  = (int*)take((size_t)n * 4);
  int*   starts  = (int*)take((size_t)n * 4);
  int*   cursor  = (int*)take((size_t)n * 4);
  int*   bsums   = (int*)take(512 * 4);
  float* tbuf    = (float*)take((size_t)n * 4);
  float* x0buf   = (float*)take((size_t)n * 4);
  int*   csr_src = (int*)take((size_t)E * 4);
  float* csr_ea  = (float*)take((size_t)E * 4);
  float* gbuf    = (float*)take((size_t)E * 4);
  float* hA      = (float*)take((size_t)n * 128 * 4);
  float* htb     = (float*)take((size_t)n * 128 * 4);
  // transient src32/tgt32 alias into htb (dead before first GEMM writes htb)
  int* src32 = (int*)htb;
  int* tgt32 = src32 + E;

  if (off > ws_size) {
    sentinel_kernel<<<ob, 256, 0, stream>>>((float*)d_out, out_size,
                                            1000.0f + (float)(ws_size >> 20));
    return;
  }

  int eb = (E + 255) / 256;
  int nb = (n + 255) / 256;  // 391 <= 512 (scan2 capacity)

  detect_kernel<<<1, 64, 0, stream>>>(ei, flag);
  cvt_kernel<<<eb, 256, 0, stream>>>(ei, E, flag, src32, tgt32);

  zero_kernel<<<nb, 256, 0, stream>>>(counts, n);
  count_kernel<<<eb, 256, 0, stream>>>(tgt32, E, n, counts);
  scan1_kernel<<<nb, 256, 0, stream>>>(counts, n, starts, bsums);
  scan2_kernel<<<1, 512, 0, stream>>>(bsums, nb);
  scan3_kernel<<<nb, 256, 0, stream>>>(starts, bsums, n, cursor);
  fill_kernel<<<eb, 256, 0, stream>>>(src32, tgt32, ea, E, n, cursor, csr_src, csr_ea);

  int sb = (int)(((size_t)n * 128 + 255) / 256);
  slice_kernel<<<sb, 256, 0, stream>>>(x, hA, x0buf, n);
  tnet2_kernel<<<(n + 63) / 64, 256, 0, stream>>>(hA, x0buf, t1W, t1b, t2W, t2b, tbuf, n);

  for (int l = 0; l < 3; l++) {
    gemm128_kernel<<<(n + 63) / 64, 256, 0, stream>>>(hA, convW[l], convb[l], htb, n);
    gates_kernel<<<eb, 256, 0, stream>>>(csr_ea, edgew[l], gbuf, E);
    agg_kernel<<<(n + 3) / 4, 256, 0, stream>>>(htb, csr_src, gbuf, starts, counts,
                                                edgew[l], hA, n);
  }

  mlp2_kernel<<<(n + 63) / 64, 256, 0, stream>>>(hA, tbuf, l1W, l1b, l2W, l2b,
                                                 (float*)d_out, n);
}

// Round 5
// 1155.813 us; speedup vs baseline: 1.4308x; 1.2628x over previous
//
#include <hip/hip_runtime.h>
#include <hip/hip_fp16.h>
#include <math.h>

// ---------------------------------------------------------------------------
// DeepECCNet: 3-layer gated graph conv + t-gate + MLP head.
// CSR (by target) built once per launch; per layer: GEMM (W in LDS, fp32
// math, fp16-packed output) -> gather-aggregate over fp16 rows (halves the
// 819 MB/layer random-gather traffic) with fused deg-normalize + ReLU.
// v5: ht stored as __half2 (512->256 B rows); agg edge-loop unrolled x4
//     (4 outstanding gathers/wave); gemm emits packed half2 (adjacent cols
//     per lane, float2 LDS weight reads).
// ---------------------------------------------------------------------------

__device__ __forceinline__ float sigmoidf_(float v) { return 1.f / (1.f + expf(-v)); }

__global__ void sentinel_kernel(float* __restrict__ out, int n, float val) {
  int i = blockIdx.x * 256 + threadIdx.x;
  if (i < n) out[i] = val;
}

__global__ void zero_kernel(int* __restrict__ p, int n) {
  int i = blockIdx.x * 256 + threadIdx.x;
  if (i < n) p[i] = 0;
}

// ---- edge-index dtype hedge: int64 has all-zero hi (odd) words -------------
__global__ void detect_kernel(const int* __restrict__ ei, int* __restrict__ flag) {
  if (threadIdx.x == 0 && blockIdx.x == 0) {
    int all0 = 1;
    for (int i = 1; i < 512; i += 2) {
      if (ei[i] != 0) { all0 = 0; break; }
    }
    *flag = all0;
  }
}

__global__ void cvt_kernel(const int* __restrict__ ei, int E, const int* __restrict__ flag,
                           int* __restrict__ src32, int* __restrict__ tgt32) {
  int e = blockIdx.x * blockDim.x + threadIdx.x;
  if (e >= E) return;
  if (*flag) {
    const long long* e64 = (const long long*)ei;
    src32[e] = (int)e64[e];
    tgt32[e] = (int)e64[(size_t)E + e];
  } else {
    src32[e] = ei[e];
    tgt32[e] = ei[(size_t)E + e];
  }
}

// ---- CSR build (all index uses bounds-guarded) -----------------------------
__global__ void count_kernel(const int* __restrict__ tgt, int E, int n,
                             int* __restrict__ counts) {
  int e = blockIdx.x * blockDim.x + threadIdx.x;
  if (e < E) {
    unsigned t = (unsigned)tgt[e];
    if (t < (unsigned)n) atomicAdd(&counts[t], 1);
  }
}

__global__ void scan1_kernel(const int* __restrict__ counts, int n,
                             int* __restrict__ starts, int* __restrict__ bsums) {
  __shared__ int tmp[256];
  int i = blockIdx.x * 256 + threadIdx.x;
  int v = (i < n) ? counts[i] : 0;
  tmp[threadIdx.x] = v;
  __syncthreads();
  for (int off = 1; off < 256; off <<= 1) {
    int t = (threadIdx.x >= (unsigned)off) ? tmp[threadIdx.x - off] : 0;
    __syncthreads();
    tmp[threadIdx.x] += t;
    __syncthreads();
  }
  if (i < n) starts[i] = tmp[threadIdx.x] - v;  // exclusive
  if (threadIdx.x == 255) bsums[blockIdx.x] = tmp[255];
}

__global__ void scan2_kernel(int* __restrict__ bsums, int nb) {
  __shared__ int tmp[512];
  int v = (threadIdx.x < (unsigned)nb) ? bsums[threadIdx.x] : 0;
  tmp[threadIdx.x] = v;
  __syncthreads();
  for (int off = 1; off < 512; off <<= 1) {
    int t = (threadIdx.x >= (unsigned)off) ? tmp[threadIdx.x - off] : 0;
    __syncthreads();
    tmp[threadIdx.x] += t;
    __syncthreads();
  }
  if (threadIdx.x < (unsigned)nb) bsums[threadIdx.x] = tmp[threadIdx.x] - v;  // exclusive
}

__global__ void scan3_kernel(int* __restrict__ starts, const int* __restrict__ bsums,
                             int n, int* __restrict__ cursor) {
  int i = blockIdx.x * 256 + threadIdx.x;
  if (i < n) {
    int s = starts[i] + bsums[blockIdx.x];
    starts[i] = s;
    cursor[i] = s;
  }
}

__global__ void fill_kernel(const int* __restrict__ src, const int* __restrict__ tgt,
                            const float* __restrict__ ea, int E, int n,
                            int* __restrict__ cursor,
                            int* __restrict__ csr_src, float* __restrict__ csr_ea) {
  int e = blockIdx.x * blockDim.x + threadIdx.x;
  if (e < E) {
    unsigned t = (unsigned)tgt[e];
    if (t >= (unsigned)n) return;
    int slot = atomicAdd(&cursor[t], 1);
    if ((unsigned)slot < (unsigned)E) {
      csr_src[slot] = src[e];
      csr_ea[slot] = ea[e];
    }
  }
}

// per-layer gate precompute (keeps expf out of the gather hot loop)
__global__ void gates_kernel(const float* __restrict__ csr_ea, const float* __restrict__ wp,
                             float* __restrict__ g, int E) {
  int e = blockIdx.x * blockDim.x + threadIdx.x;
  if (e < E) g[e] = sigmoidf_(csr_ea[e] * wp[0]);
}

// ---- h0 = x[:, 1:]; x0 = x[:, 0] ------------------------------------------
__global__ void slice_kernel(const float* __restrict__ x, float* __restrict__ h,
                             float* __restrict__ x0, int n) {
  int idx = blockIdx.x * blockDim.x + threadIdx.x;
  if (idx < n * 128) {
    int node = idx >> 7;
    int k = idx & 127;
    h[idx] = x[(size_t)node * 129 + 1 + k];
  }
  if (idx < n) x0[idx] = x[(size_t)idx * 129];
}

// ---- t path (GEMM-style): t = sigmoid(relu([x0,hA]@t1W+t1b)@t2W+t2b) -------
__global__ __launch_bounds__(256) void tnet2_kernel(const float* __restrict__ hA,
    const float* __restrict__ x0, const float* __restrict__ t1W,
    const float* __restrict__ t1b, const float* __restrict__ t2W,
    const float* __restrict__ t2b, float* __restrict__ t, int n) {
  __shared__ float sW[128 * 64];  // t1W rows k=1..128
  __shared__ float sW0[64], sB[64], sT2[64];
  for (int i = threadIdx.x; i < 128 * 64; i += 256) {
    int k = i >> 6, o = i & 63;
    sW[i] = t1W[(k + 1) * 64 + o];
  }
  if (threadIdx.x < 64) {
    sW0[threadIdx.x] = t1W[threadIdx.x];
    sB[threadIdx.x] = t1b[threadIdx.x];
    sT2[threadIdx.x] = t2W[threadIdx.x];
  }
  __syncthreads();
  int wv = threadIdx.x >> 6, lane = threadIdx.x & 63;
  int base = (blockIdx.x * 4 + wv) * 16;
  if (base >= n) return;
  float w0 = sW0[lane], bb = sB[lane], t2 = sT2[lane];
  float t2b0 = t2b[0];
  for (int g = 0; g < 2; g++) {
    int n0 = base + g * 8;
    if (n0 >= n) break;
    const float4* hp[8];
    float acc[8];
#pragma unroll
    for (int i = 0; i < 8; i++) {
      int id = min(n0 + i, n - 1);
      hp[i] = (const float4*)(hA + (size_t)id * 128);
      acc[i] = bb + x0[id] * w0;
    }
    for (int k4 = 0; k4 < 32; k4++) {
      float4 v[8];
#pragma unroll
      for (int i = 0; i < 8; i++) v[i] = hp[i][k4];
#pragma unroll
      for (int kk = 0; kk < 4; kk++) {
        float w = sW[(k4 * 4 + kk) * 64 + lane];
#pragma unroll
        for (int i = 0; i < 8; i++) acc[i] += ((const float*)&v[i])[kk] * w;
      }
    }
#pragma unroll
    for (int i = 0; i < 8; i++) {
      float p = fmaxf(acc[i], 0.f) * t2;
      for (int off2 = 32; off2; off2 >>= 1) p += __shfl_down(p, off2);
      if (lane == 0 && n0 + i < n) t[n0 + i] = sigmoidf_(p + t2b0);
    }
  }
}

// ---- head (GEMM-style): out = sigmoid(relu([h,t]@l1W+l1b)@l2W+l2b) ---------
__global__ __launch_bounds__(256) void mlp2_kernel(const float* __restrict__ h,
    const float* __restrict__ t, const float* __restrict__ l1W,
    const float* __restrict__ l1b, const float* __restrict__ l2W,
    const float* __restrict__ l2b, float* __restrict__ out, int n) {
  __shared__ float sW[128 * 64];
  __shared__ float sWt[64], sB[64], sL2[64];
  for (int i = threadIdx.x; i < 128 * 64; i += 256) sW[i] = l1W[i];
  if (threadIdx.x < 64) {
    sWt[threadIdx.x] = l1W[128 * 64 + threadIdx.x];
    sB[threadIdx.x] = l1b[threadIdx.x];
    sL2[threadIdx.x] = l2W[threadIdx.x];
  }
  __syncthreads();
  int wv = threadIdx.x >> 6, lane = threadIdx.x & 63;
  int base = (blockIdx.x * 4 + wv) * 16;
  if (base >= n) return;
  float wt = sWt[lane], bb = sB[lane], l2 = sL2[lane];
  float l2b0 = l2b[0];
  for (int g = 0; g < 2; g++) {
    int n0 = base + g * 8;
    if (n0 >= n) break;
    const float4* hp[8];
    float acc[8];
#pragma unroll
    for (int i = 0; i < 8; i++) {
      int id = min(n0 + i, n - 1);
      hp[i] = (const float4*)(h + (size_t)id * 128);
      acc[i] = bb + t[id] * wt;
    }
    for (int k4 = 0; k4 < 32; k4++) {
      float4 v[8];
#pragma unroll
      for (int i = 0; i < 8; i++) v[i] = hp[i][k4];
#pragma unroll
      for (int kk = 0; kk < 4; kk++) {
        float w = sW[(k4 * 4 + kk) * 64 + lane];
#pragma unroll
        for (int i = 0; i < 8; i++) acc[i] += ((const float*)&v[i])[kk] * w;
      }
    }
#pragma unroll
    for (int i = 0; i < 8; i++) {
      float p = fmaxf(acc[i], 0.f) * l2;
      for (int off2 = 32; off2; off2 >>= 1) p += __shfl_down(p, off2);
      if (lane == 0 && n0 + i < n) out[n0 + i] = sigmoidf_(p + l2b0);
    }
  }
}

// ---- GEMM: ht16 = half2(h @ W + b)  (lane handles cols 2*lane, 2*lane+1) ---
__global__ __launch_bounds__(256) void gemm128_kernel(const float* __restrict__ h,
    const float* __restrict__ Wg, const float* __restrict__ b,
    __half2* __restrict__ out16, int n) {
  __shared__ float sW[16384];  // 64 KB
  {
    float4* d = (float4*)sW;
    const float4* s = (const float4*)Wg;
    for (int i = threadIdx.x; i < 4096; i += 256) d[i] = s[i];
  }
  __syncthreads();
  int wv = threadIdx.x >> 6, lane = threadIdx.x & 63;
  int base = (blockIdx.x * 4 + wv) * 16;
  float b0 = b[2 * lane], b1 = b[2 * lane + 1];
  for (int g = 0; g < 4; g++) {
    int n0 = base + g * 4;
    if (n0 >= n) break;
    int i1 = min(n0 + 1, n - 1), i2 = min(n0 + 2, n - 1), i3 = min(n0 + 3, n - 1);
    const float4* h0 = (const float4*)(h + (size_t)n0 * 128);
    const float4* h1 = (const float4*)(h + (size_t)i1 * 128);
    const float4* h2 = (const float4*)(h + (size_t)i2 * 128);
    const float4* h3 = (const float4*)(h + (size_t)i3 * 128);
    float a00 = b0, a01 = b1, a10 = b0, a11 = b1;
    float a20 = b0, a21 = b1, a30 = b0, a31 = b1;
    for (int k4 = 0; k4 < 32; k4++) {
      float4 v0 = h0[k4], v1 = h1[k4], v2 = h2[k4], v3 = h3[k4];
      const float* e0 = (const float*)&v0;
      const float* e1 = (const float*)&v1;
      const float* e2 = (const float*)&v2;
      const float* e3 = (const float*)&v3;
#pragma unroll
      for (int kk = 0; kk < 4; kk++) {
        float2 w = ((const float2*)(sW + (k4 * 4 + kk) * 128))[lane];  // ds_read_b64
        a00 += e0[kk] * w.x; a01 += e0[kk] * w.y;
        a10 += e1[kk] * w.x; a11 += e1[kk] * w.y;
        a20 += e2[kk] * w.x; a21 += e2[kk] * w.y;
        a30 += e3[kk] * w.x; a31 += e3[kk] * w.y;
      }
    }
    size_t o0 = (size_t)n0 * 64;
    out16[o0 + lane] = __floats2half2_rn(a00, a01);
    if (n0 + 1 < n) out16[o0 + 64 + lane] = __floats2half2_rn(a10, a11);
    if (n0 + 2 < n) out16[o0 + 128 + lane] = __floats2half2_rn(a20, a21);
    if (n0 + 3 < n) out16[o0 + 192 + lane] = __floats2half2_rn(a30, a31);
  }
}

// ---- aggregation over fp16 rows, edge loop unrolled x4 ---------------------
// h' = relu( (sig(w)*ht[v] + sum_e g_e*ht[src_e]) / (deg+1) ), fp32 out.
__global__ __launch_bounds__(256) void agg_kernel(const __half2* __restrict__ ht,
    const int* __restrict__ csr_src, const float* __restrict__ gates,
    const int* __restrict__ starts, const int* __restrict__ counts,
    const float* __restrict__ wp, float* __restrict__ hout, int n) {
  int wv = threadIdx.x >> 6, lane = threadIdx.x & 63;
  int node = blockIdx.x * 4 + wv;
  if (node >= n) return;
  int s = starts[node], c = counts[node];
  float gs = sigmoidf_(wp[0]);
  float2 v0 = __half22float2(ht[(size_t)node * 64 + lane]);
  float ax = gs * v0.x, ay = gs * v0.y;
  float bx = 0.f, by = 0.f;
  int j = 0;
  for (; j + 4 <= c; j += 4) {
    int sn0 = csr_src[s + j],     sn1 = csr_src[s + j + 1];
    int sn2 = csr_src[s + j + 2], sn3 = csr_src[s + j + 3];
    float g0 = gates[s + j],     g1 = gates[s + j + 1];
    float g2 = gates[s + j + 2], g3 = gates[s + j + 3];
    sn0 = min(max(sn0, 0), n - 1); sn1 = min(max(sn1, 0), n - 1);
    sn2 = min(max(sn2, 0), n - 1); sn3 = min(max(sn3, 0), n - 1);
    float2 f0 = __half22float2(ht[(size_t)sn0 * 64 + lane]);
    float2 f1 = __half22float2(ht[(size_t)sn1 * 64 + lane]);
    float2 f2 = __half22float2(ht[(size_t)sn2 * 64 + lane]);
    float2 f3 = __half22float2(ht[(size_t)sn3 * 64 + lane]);
    ax += g0 * f0.x; ay += g0 * f0.y;
    bx += g1 * f1.x; by += g1 * f1.y;
    ax += g2 * f2.x; ay += g2 * f2.y;
    bx += g3 * f3.x; by += g3 * f3.y;
  }
  for (; j < c; j++) {
    int sn = min(max(csr_src[s + j], 0), n - 1);
    float g = gates[s + j];
    float2 f = __half22float2(ht[(size_t)sn * 64 + lane]);
    ax += g * f.x; ay += g * f.y;
  }
  ax += bx; ay += by;
  float inv = 1.f / (float)(c + 1);
  ax = fmaxf(ax * inv, 0.f);
  ay = fmaxf(ay * inv, 0.f);
  ((float2*)(hout + (size_t)node * 128))[lane] = make_float2(ax, ay);
}

// ---------------------------------------------------------------------------
extern "C" void kernel_launch(void* const* d_in, const int* in_sizes, int n_in,
                              void* d_out, int out_size, void* d_ws, size_t ws_size,
                              hipStream_t stream) {
  int ob = (out_size + 255) / 256;

  const float *x, *ea, *l1W, *l1b, *l2W, *l2b, *t1W, *t1b, *t2W, *t2b;
  const float *convW[3], *convb[3], *edgew[3];
  const int* ei;

  if (n_in == 20) {          // tuples flattened to separate entries
    x = (const float*)d_in[0]; ei = (const int*)d_in[1]; ea = (const float*)d_in[2];
    for (int l = 0; l < 3; l++) {
      convW[l] = (const float*)d_in[3 + l];
      convb[l] = (const float*)d_in[6 + l];
      edgew[l] = (const float*)d_in[9 + l];
    }
    l1W = (const float*)d_in[12]; l1b = (const float*)d_in[13];
    l2W = (const float*)d_in[14]; l2b = (const float*)d_in[15];
    t1W = (const float*)d_in[16]; t1b = (const float*)d_in[17];
    t2W = (const float*)d_in[18]; t2b = (const float*)d_in[19];
  } else if (n_in == 14) {   // each tuple is ONE concatenated buffer
    x = (const float*)d_in[0]; ei = (const int*)d_in[1]; ea = (const float*)d_in[2];
    const float* cw = (const float*)d_in[3];
    const float* cb = (const float*)d_in[4];
    const float* ew = (const float*)d_in[5];
    for (int l = 0; l < 3; l++) {
      convW[l] = cw + (size_t)l * 128 * 128;
      convb[l] = cb + (size_t)l * 128;
      edgew[l] = ew + l;
    }
    l1W = (const float*)d_in[6];  l1b = (const float*)d_in[7];
    l2W = (const float*)d_in[8];  l2b = (const float*)d_in[9];
    t1W = (const float*)d_in[10]; t1b = (const float*)d_in[11];
    t2W = (const float*)d_in[12]; t2b = (const float*)d_in[13];
  } else {
    sentinel_kernel<<<ob, 256, 0, stream>>>((float*)d_out, out_size,
                                            900.0f + (float)n_in);
    return;
  }

  int n = in_sizes[0] / 129;   // 100000
  int E = in_sizes[2];         // 1600000

  char* ws = (char*)d_ws;
  size_t off = 0;
  auto take = [&](size_t bytes) -> void* {
    void* p = ws + off;
    off = (off + bytes + 255) & ~(size_t)255;
    return p;
  };
  int*     flag    = (int*)take(256);
  int*     counts  = (int*)take((size_t)n * 4);
  int*     starts  = (int*)take((size_t)n * 4);
  int*     cursor  = (int*)take((size_t)n * 4);
  int*     bsums   = (int*)take(512 * 4);
  float*   tbuf    = (float*)take((size_t)n * 4);
  float*   x0buf   = (float*)take((size_t)n * 4);
  int*     csr_src = (int*)take((size_t)E * 4);
  float*   csr_ea  = (float*)take((size_t)E * 4);
  float*   gbuf    = (float*)take((size_t)E * 4);
  float*   hA      = (float*)take((size_t)n * 128 * 4);
  __half2* ht16    = (__half2*)take((size_t)n * 64 * 4);  // 25.6 MB
  // transient src32/tgt32 alias into ht16 (dead before first GEMM writes it)
  int* src32 = (int*)ht16;
  int* tgt32 = src32 + E;   // 2*E*4 = 12.8 MB <= 25.6 MB

  if (off > ws_size) {
    sentinel_kernel<<<ob, 256, 0, stream>>>((float*)d_out, out_size,
                                            1000.0f + (float)(ws_size >> 20));
    return;
  }

  int eb = (E + 255) / 256;
  int nb = (n + 255) / 256;  // 391 <= 512 (scan2 capacity)

  detect_kernel<<<1, 64, 0, stream>>>(ei, flag);
  cvt_kernel<<<eb, 256, 0, stream>>>(ei, E, flag, src32, tgt32);

  zero_kernel<<<nb, 256, 0, stream>>>(counts, n);
  count_kernel<<<eb, 256, 0, stream>>>(tgt32, E, n, counts);
  scan1_kernel<<<nb, 256, 0, stream>>>(counts, n, starts, bsums);
  scan2_kernel<<<1, 512, 0, stream>>>(bsums, nb);
  scan3_kernel<<<nb, 256, 0, stream>>>(starts, bsums, n, cursor);
  fill_kernel<<<eb, 256, 0, stream>>>(src32, tgt32, ea, E, n, cursor, csr_src, csr_ea);

  int sb = (int)(((size_t)n * 128 + 255) / 256);
  slice_kernel<<<sb, 256, 0, stream>>>(x, hA, x0buf, n);
  tnet2_kernel<<<(n + 63) / 64, 256, 0, stream>>>(hA, x0buf, t1W, t1b, t2W, t2b, tbuf, n);

  for (int l = 0; l < 3; l++) {
    gemm128_kernel<<<(n + 63) / 64, 256, 0, stream>>>(hA, convW[l], convb[l], ht16, n);
    gates_kernel<<<eb, 256, 0, stream>>>(csr_ea, edgew[l], gbuf, E);
    agg_kernel<<<(n + 3) / 4, 256, 0, stream>>>(ht16, csr_src, gbuf, starts, counts,
                                                edgew[l], hA, n);
  }

  mlp2_kernel<<<(n + 63) / 64, 256, 0, stream>>>(hA, tbuf, l1W, l1b, l2W, l2b,
                                                 (float*)d_out, n);
}

// Round 6
// 905.377 us; speedup vs baseline: 1.8266x; 1.2766x over previous
//
#include <hip/hip_runtime.h>
#include <hip/hip_fp16.h>
#include <math.h>

// ---------------------------------------------------------------------------
// DeepECCNet: 3-layer gated graph conv + t-gate + MLP head.
// v6: conv GEMM moved to MFMA (mfma_f32_16x16x32_f16). W staged per-block
//     into LDS pre-swizzled into B-fragment order (32 KB fp16 -> 5 blocks/CU
//     vs v5's 64 KB fp32 -> 2 blocks/CU, which left the vector GEMM at 19%
//     occupancy / 25% VALUBusy / 132 us). A-frags converted fp32->fp16 at
//     load; fp32 accumulate; bias fused in epilogue; fp16 output feeds the
//     gather (agg) unchanged.
// Layouts (docs, m89/m120-verified): A[m=lane&15][k=(lane>>4)*8+j],
// B[k=(lane>>4)*8+j][n=lane&15], D col=lane&15 row=(lane>>4)*4+reg.
// ---------------------------------------------------------------------------

typedef _Float16 f16x8 __attribute__((ext_vector_type(8)));
typedef float f32x4 __attribute__((ext_vector_type(4)));

__device__ __forceinline__ float sigmoidf_(float v) { return 1.f / (1.f + expf(-v)); }

__global__ void sentinel_kernel(float* __restrict__ out, int n, float val) {
  int i = blockIdx.x * 256 + threadIdx.x;
  if (i < n) out[i] = val;
}

__global__ void zero_kernel(int* __restrict__ p, int n) {
  int i = blockIdx.x * 256 + threadIdx.x;
  if (i < n) p[i] = 0;
}

// ---- edge-index dtype hedge: int64 has all-zero hi (odd) words -------------
__global__ void detect_kernel(const int* __restrict__ ei, int* __restrict__ flag) {
  if (threadIdx.x == 0 && blockIdx.x == 0) {
    int all0 = 1;
    for (int i = 1; i < 512; i += 2) {
      if (ei[i] != 0) { all0 = 0; break; }
    }
    *flag = all0;
  }
}

__global__ void cvt_kernel(const int* __restrict__ ei, int E, const int* __restrict__ flag,
                           int* __restrict__ src32, int* __restrict__ tgt32) {
  int e = blockIdx.x * blockDim.x + threadIdx.x;
  if (e >= E) return;
  if (*flag) {
    const long long* e64 = (const long long*)ei;
    src32[e] = (int)e64[e];
    tgt32[e] = (int)e64[(size_t)E + e];
  } else {
    src32[e] = ei[e];
    tgt32[e] = ei[(size_t)E + e];
  }
}

// ---- CSR build (all index uses bounds-guarded) -----------------------------
__global__ void count_kernel(const int* __restrict__ tgt, int E, int n,
                             int* __restrict__ counts) {
  int e = blockIdx.x * blockDim.x + threadIdx.x;
  if (e < E) {
    unsigned t = (unsigned)tgt[e];
    if (t < (unsigned)n) atomicAdd(&counts[t], 1);
  }
}

__global__ void scan1_kernel(const int* __restrict__ counts, int n,
                             int* __restrict__ starts, int* __restrict__ bsums) {
  __shared__ int tmp[256];
  int i = blockIdx.x * 256 + threadIdx.x;
  int v = (i < n) ? counts[i] : 0;
  tmp[threadIdx.x] = v;
  __syncthreads();
  for (int off = 1; off < 256; off <<= 1) {
    int t = (threadIdx.x >= (unsigned)off) ? tmp[threadIdx.x - off] : 0;
    __syncthreads();
    tmp[threadIdx.x] += t;
    __syncthreads();
  }
  if (i < n) starts[i] = tmp[threadIdx.x] - v;  // exclusive
  if (threadIdx.x == 255) bsums[blockIdx.x] = tmp[255];
}

__global__ void scan2_kernel(int* __restrict__ bsums, int nb) {
  __shared__ int tmp[512];
  int v = (threadIdx.x < (unsigned)nb) ? bsums[threadIdx.x] : 0;
  tmp[threadIdx.x] = v;
  __syncthreads();
  for (int off = 1; off < 512; off <<= 1) {
    int t = (threadIdx.x >= (unsigned)off) ? tmp[threadIdx.x - off] : 0;
    __syncthreads();
    tmp[threadIdx.x] += t;
    __syncthreads();
  }
  if (threadIdx.x < (unsigned)nb) bsums[threadIdx.x] = tmp[threadIdx.x] - v;  // exclusive
}

__global__ void scan3_kernel(int* __restrict__ starts, const int* __restrict__ bsums,
                             int n, int* __restrict__ cursor) {
  int i = blockIdx.x * 256 + threadIdx.x;
  if (i < n) {
    int s = starts[i] + bsums[blockIdx.x];
    starts[i] = s;
    cursor[i] = s;
  }
}

__global__ void fill_kernel(const int* __restrict__ src, const int* __restrict__ tgt,
                            const float* __restrict__ ea, int E, int n,
                            int* __restrict__ cursor,
                            int* __restrict__ csr_src, float* __restrict__ csr_ea) {
  int e = blockIdx.x * blockDim.x + threadIdx.x;
  if (e < E) {
    unsigned t = (unsigned)tgt[e];
    if (t >= (unsigned)n) return;
    int slot = atomicAdd(&cursor[t], 1);
    if ((unsigned)slot < (unsigned)E) {
      csr_src[slot] = src[e];
      csr_ea[slot] = ea[e];
    }
  }
}

// per-layer gate precompute (keeps expf out of the gather hot loop)
__global__ void gates_kernel(const float* __restrict__ csr_ea, const float* __restrict__ wp,
                             float* __restrict__ g, int E) {
  int e = blockIdx.x * blockDim.x + threadIdx.x;
  if (e < E) g[e] = sigmoidf_(csr_ea[e] * wp[0]);
}

// ---- h0 = x[:, 1:]; x0 = x[:, 0] ------------------------------------------
__global__ void slice_kernel(const float* __restrict__ x, float* __restrict__ h,
                             float* __restrict__ x0, int n) {
  int idx = blockIdx.x * blockDim.x + threadIdx.x;
  if (idx < n * 128) {
    int node = idx >> 7;
    int k = idx & 127;
    h[idx] = x[(size_t)node * 129 + 1 + k];
  }
  if (idx < n) x0[idx] = x[(size_t)idx * 129];
}

// ---- t path (GEMM-style): t = sigmoid(relu([x0,hA]@t1W+t1b)@t2W+t2b) -------
__global__ __launch_bounds__(256) void tnet2_kernel(const float* __restrict__ hA,
    const float* __restrict__ x0, const float* __restrict__ t1W,
    const float* __restrict__ t1b, const float* __restrict__ t2W,
    const float* __restrict__ t2b, float* __restrict__ t, int n) {
  __shared__ float sW[128 * 64];  // t1W rows k=1..128
  __shared__ float sW0[64], sB[64], sT2[64];
  for (int i = threadIdx.x; i < 128 * 64; i += 256) {
    int k = i >> 6, o = i & 63;
    sW[i] = t1W[(k + 1) * 64 + o];
  }
  if (threadIdx.x < 64) {
    sW0[threadIdx.x] = t1W[threadIdx.x];
    sB[threadIdx.x] = t1b[threadIdx.x];
    sT2[threadIdx.x] = t2W[threadIdx.x];
  }
  __syncthreads();
  int wv = threadIdx.x >> 6, lane = threadIdx.x & 63;
  int base = (blockIdx.x * 4 + wv) * 16;
  if (base >= n) return;
  float w0 = sW0[lane], bb = sB[lane], t2 = sT2[lane];
  float t2b0 = t2b[0];
  for (int g = 0; g < 2; g++) {
    int n0 = base + g * 8;
    if (n0 >= n) break;
    const float4* hp[8];
    float acc[8];
#pragma unroll
    for (int i = 0; i < 8; i++) {
      int id = min(n0 + i, n - 1);
      hp[i] = (const float4*)(hA + (size_t)id * 128);
      acc[i] = bb + x0[id] * w0;
    }
    for (int k4 = 0; k4 < 32; k4++) {
      float4 v[8];
#pragma unroll
      for (int i = 0; i < 8; i++) v[i] = hp[i][k4];
#pragma unroll
      for (int kk = 0; kk < 4; kk++) {
        float w = sW[(k4 * 4 + kk) * 64 + lane];
#pragma unroll
        for (int i = 0; i < 8; i++) acc[i] += ((const float*)&v[i])[kk] * w;
      }
    }
#pragma unroll
    for (int i = 0; i < 8; i++) {
      float p = fmaxf(acc[i], 0.f) * t2;
      for (int off2 = 32; off2; off2 >>= 1) p += __shfl_down(p, off2);
      if (lane == 0 && n0 + i < n) t[n0 + i] = sigmoidf_(p + t2b0);
    }
  }
}

// ---- head (GEMM-style): out = sigmoid(relu([h,t]@l1W+l1b)@l2W+l2b) ---------
__global__ __launch_bounds__(256) void mlp2_kernel(const float* __restrict__ h,
    const float* __restrict__ t, const float* __restrict__ l1W,
    const float* __restrict__ l1b, const float* __restrict__ l2W,
    const float* __restrict__ l2b, float* __restrict__ out, int n) {
  __shared__ float sW[128 * 64];
  __shared__ float sWt[64], sB[64], sL2[64];
  for (int i = threadIdx.x; i < 128 * 64; i += 256) sW[i] = l1W[i];
  if (threadIdx.x < 64) {
    sWt[threadIdx.x] = l1W[128 * 64 + threadIdx.x];
    sB[threadIdx.x] = l1b[threadIdx.x];
    sL2[threadIdx.x] = l2W[threadIdx.x];
  }
  __syncthreads();
  int wv = threadIdx.x >> 6, lane = threadIdx.x & 63;
  int base = (blockIdx.x * 4 + wv) * 16;
  if (base >= n) return;
  float wt = sWt[lane], bb = sB[lane], l2 = sL2[lane];
  float l2b0 = l2b[0];
  for (int g = 0; g < 2; g++) {
    int n0 = base + g * 8;
    if (n0 >= n) break;
    const float4* hp[8];
    float acc[8];
#pragma unroll
    for (int i = 0; i < 8; i++) {
      int id = min(n0 + i, n - 1);
      hp[i] = (const float4*)(h + (size_t)id * 128);
      acc[i] = bb + t[id] * wt;
    }
    for (int k4 = 0; k4 < 32; k4++) {
      float4 v[8];
#pragma unroll
      for (int i = 0; i < 8; i++) v[i] = hp[i][k4];
#pragma unroll
      for (int kk = 0; kk < 4; kk++) {
        float w = sW[(k4 * 4 + kk) * 64 + lane];
#pragma unroll
        for (int i = 0; i < 8; i++) acc[i] += ((const float*)&v[i])[kk] * w;
      }
    }
#pragma unroll
    for (int i = 0; i < 8; i++) {
      float p = fmaxf(acc[i], 0.f) * l2;
      for (int off2 = 32; off2; off2 >>= 1) p += __shfl_down(p, off2);
      if (lane == 0 && n0 + i < n) out[n0 + i] = sigmoidf_(p + l2b0);
    }
  }
}

// ---- MFMA GEMM: ht16 = f16(h @ W + b) --------------------------------------
// Wave computes 16 nodes x 128 cols (8 acc tiles); K-loop 4 steps of 32.
// W pre-swizzled into LDS in B-frag order so each frag is one ds_read_b128.
__global__ __launch_bounds__(256) void gemm_mfma_kernel(const float* __restrict__ h,
    const float* __restrict__ Wg, const float* __restrict__ b,
    _Float16* __restrict__ out16, int n) {
  // entry (ks, nt, lane): 8 halves = W[ks*32+(lane>>4)*8+j][nt*16+(lane&15)]
  __shared__ __align__(16) _Float16 sB[4 * 8 * 64 * 8];  // 32 KB
  for (int i = threadIdx.x; i < 4096; i += 256) {  // i = float4 index over W
    int k = i >> 5;
    int n4 = (i & 31) * 4;
    float4 w4 = ((const float4*)Wg)[i];
    int ks = k >> 5, quad = (k >> 3) & 3, j = k & 7;
#pragma unroll
    for (int c = 0; c < 4; c++) {
      int col = n4 + c;
      int nt = col >> 4, cl = col & 15;
      sB[(((ks * 8 + nt) * 64) + quad * 16 + cl) * 8 + j] =
          (_Float16)((const float*)&w4)[c];
    }
  }
  __syncthreads();
  int wv = threadIdx.x >> 6, lane = threadIdx.x & 63;
  int quad = lane >> 4, l15 = lane & 15;
  int n0 = (blockIdx.x * 4 + wv) * 16;
  if (n0 >= n) return;
  int node_a = min(n0 + l15, n - 1);
  const float* hrow = h + (size_t)node_a * 128 + quad * 8;

  f32x4 acc[8];
#pragma unroll
  for (int t = 0; t < 8; t++) acc[t] = (f32x4){0.f, 0.f, 0.f, 0.f};

  for (int ks = 0; ks < 4; ks++) {
    float4 a0 = ((const float4*)(hrow + ks * 32))[0];
    float4 a1 = ((const float4*)(hrow + ks * 32))[1];
    f16x8 afrag;
    afrag[0] = (_Float16)a0.x; afrag[1] = (_Float16)a0.y;
    afrag[2] = (_Float16)a0.z; afrag[3] = (_Float16)a0.w;
    afrag[4] = (_Float16)a1.x; afrag[5] = (_Float16)a1.y;
    afrag[6] = (_Float16)a1.z; afrag[7] = (_Float16)a1.w;
    const f16x8* bp = (const f16x8*)(sB + ks * 8 * 64 * 8);
#pragma unroll
    for (int t = 0; t < 8; t++) {
      f16x8 bfrag = bp[t * 64 + lane];
      acc[t] = __builtin_amdgcn_mfma_f32_16x16x32_f16(afrag, bfrag, acc[t], 0, 0, 0);
    }
  }
  // D: col = l15 (within tile), row = quad*4 + reg
#pragma unroll
  for (int t = 0; t < 8; t++) {
    float bias = b[t * 16 + l15];
#pragma unroll
    for (int r = 0; r < 4; r++) {
      int node = n0 + quad * 4 + r;
      if (node < n)
        out16[(size_t)node * 128 + t * 16 + l15] = (_Float16)(acc[t][r] + bias);
    }
  }
}

// ---- aggregation over fp16 rows, edge loop unrolled x4 ---------------------
// h' = relu( (sig(w)*ht[v] + sum_e g_e*ht[src_e]) / (deg+1) ), fp32 out.
__global__ __launch_bounds__(256) void agg_kernel(const __half2* __restrict__ ht,
    const int* __restrict__ csr_src, const float* __restrict__ gates,
    const int* __restrict__ starts, const int* __restrict__ counts,
    const float* __restrict__ wp, float* __restrict__ hout, int n) {
  int wv = threadIdx.x >> 6, lane = threadIdx.x & 63;
  int node = blockIdx.x * 4 + wv;
  if (node >= n) return;
  int s = starts[node], c = counts[node];
  float gs = sigmoidf_(wp[0]);
  float2 v0 = __half22float2(ht[(size_t)node * 64 + lane]);
  float ax = gs * v0.x, ay = gs * v0.y;
  float bx = 0.f, by = 0.f;
  int j = 0;
  for (; j + 4 <= c; j += 4) {
    int sn0 = csr_src[s + j],     sn1 = csr_src[s + j + 1];
    int sn2 = csr_src[s + j + 2], sn3 = csr_src[s + j + 3];
    float g0 = gates[s + j],     g1 = gates[s + j + 1];
    float g2 = gates[s + j + 2], g3 = gates[s + j + 3];
    sn0 = min(max(sn0, 0), n - 1); sn1 = min(max(sn1, 0), n - 1);
    sn2 = min(max(sn2, 0), n - 1); sn3 = min(max(sn3, 0), n - 1);
    float2 f0 = __half22float2(ht[(size_t)sn0 * 64 + lane]);
    float2 f1 = __half22float2(ht[(size_t)sn1 * 64 + lane]);
    float2 f2 = __half22float2(ht[(size_t)sn2 * 64 + lane]);
    float2 f3 = __half22float2(ht[(size_t)sn3 * 64 + lane]);
    ax += g0 * f0.x; ay += g0 * f0.y;
    bx += g1 * f1.x; by += g1 * f1.y;
    ax += g2 * f2.x; ay += g2 * f2.y;
    bx += g3 * f3.x; by += g3 * f3.y;
  }
  for (; j < c; j++) {
    int sn = min(max(csr_src[s + j], 0), n - 1);
    float g = gates[s + j];
    float2 f = __half22float2(ht[(size_t)sn * 64 + lane]);
    ax += g * f.x; ay += g * f.y;
  }
  ax += bx; ay += by;
  float inv = 1.f / (float)(c + 1);
  ax = fmaxf(ax * inv, 0.f);
  ay = fmaxf(ay * inv, 0.f);
  ((float2*)(hout + (size_t)node * 128))[lane] = make_float2(ax, ay);
}

// ---------------------------------------------------------------------------
extern "C" void kernel_launch(void* const* d_in, const int* in_sizes, int n_in,
                              void* d_out, int out_size, void* d_ws, size_t ws_size,
                              hipStream_t stream) {
  int ob = (out_size + 255) / 256;

  const float *x, *ea, *l1W, *l1b, *l2W, *l2b, *t1W, *t1b, *t2W, *t2b;
  const float *convW[3], *convb[3], *edgew[3];
  const int* ei;

  if (n_in == 20) {          // tuples flattened to separate entries
    x = (const float*)d_in[0]; ei = (const int*)d_in[1]; ea = (const float*)d_in[2];
    for (int l = 0; l < 3; l++) {
      convW[l] = (const float*)d_in[3 + l];
      convb[l] = (const float*)d_in[6 + l];
      edgew[l] = (const float*)d_in[9 + l];
    }
    l1W = (const float*)d_in[12]; l1b = (const float*)d_in[13];
    l2W = (const float*)d_in[14]; l2b = (const float*)d_in[15];
    t1W = (const float*)d_in[16]; t1b = (const float*)d_in[17];
    t2W = (const float*)d_in[18]; t2b = (const float*)d_in[19];
  } else if (n_in == 14) {   // each tuple is ONE concatenated buffer
    x = (const float*)d_in[0]; ei = (const int*)d_in[1]; ea = (const float*)d_in[2];
    const float* cw = (const float*)d_in[3];
    const float* cb = (const float*)d_in[4];
    const float* ew = (const float*)d_in[5];
    for (int l = 0; l < 3; l++) {
      convW[l] = cw + (size_t)l * 128 * 128;
      convb[l] = cb + (size_t)l * 128;
      edgew[l] = ew + l;
    }
    l1W = (const float*)d_in[6];  l1b = (const float*)d_in[7];
    l2W = (const float*)d_in[8];  l2b = (const float*)d_in[9];
    t1W = (const float*)d_in[10]; t1b = (const float*)d_in[11];
    t2W = (const float*)d_in[12]; t2b = (const float*)d_in[13];
  } else {
    sentinel_kernel<<<ob, 256, 0, stream>>>((float*)d_out, out_size,
                                            900.0f + (float)n_in);
    return;
  }

  int n = in_sizes[0] / 129;   // 100000
  int E = in_sizes[2];         // 1600000

  char* ws = (char*)d_ws;
  size_t off = 0;
  auto take = [&](size_t bytes) -> void* {
    void* p = ws + off;
    off = (off + bytes + 255) & ~(size_t)255;
    return p;
  };
  int*      flag    = (int*)take(256);
  int*      counts  = (int*)take((size_t)n * 4);
  int*      starts  = (int*)take((size_t)n * 4);
  int*      cursor  = (int*)take((size_t)n * 4);
  int*      bsums   = (int*)take(512 * 4);
  float*    tbuf    = (float*)take((size_t)n * 4);
  float*    x0buf   = (float*)take((size_t)n * 4);
  int*      csr_src = (int*)take((size_t)E * 4);
  float*    csr_ea  = (float*)take((size_t)E * 4);
  float*    gbuf    = (float*)take((size_t)E * 4);
  float*    hA      = (float*)take((size_t)n * 128 * 4);
  _Float16* ht16    = (_Float16*)take((size_t)n * 128 * 2);  // 25.6 MB
  // transient src32/tgt32 alias into ht16 (dead before first GEMM writes it)
  int* src32 = (int*)ht16;
  int* tgt32 = src32 + E;   // 2*E*4 = 12.8 MB <= 25.6 MB

  if (off > ws_size) {
    sentinel_kernel<<<ob, 256, 0, stream>>>((float*)d_out, out_size,
                                            1000.0f + (float)(ws_size >> 20));
    return;
  }

  int eb = (E + 255) / 256;
  int nb = (n + 255) / 256;  // 391 <= 512 (scan2 capacity)

  detect_kernel<<<1, 64, 0, stream>>>(ei, flag);
  cvt_kernel<<<eb, 256, 0, stream>>>(ei, E, flag, src32, tgt32);

  zero_kernel<<<nb, 256, 0, stream>>>(counts, n);
  count_kernel<<<eb, 256, 0, stream>>>(tgt32, E, n, counts);
  scan1_kernel<<<nb, 256, 0, stream>>>(counts, n, starts, bsums);
  scan2_kernel<<<1, 512, 0, stream>>>(bsums, nb);
  scan3_kernel<<<nb, 256, 0, stream>>>(starts, bsums, n, cursor);
  fill_kernel<<<eb, 256, 0, stream>>>(src32, tgt32, ea, E, n, cursor, csr_src, csr_ea);

  int sb = (int)(((size_t)n * 128 + 255) / 256);
  slice_kernel<<<sb, 256, 0, stream>>>(x, hA, x0buf, n);
  tnet2_kernel<<<(n + 63) / 64, 256, 0, stream>>>(hA, x0buf, t1W, t1b, t2W, t2b, tbuf, n);

  for (int l = 0; l < 3; l++) {
    gemm_mfma_kernel<<<(n + 63) / 64, 256, 0, stream>>>(hA, convW[l], convb[l], ht16, n);
    gates_kernel<<<eb, 256, 0, stream>>>(csr_ea, edgew[l], gbuf, E);
    agg_kernel<<<(n + 3) / 4, 256, 0, stream>>>((const __half2*)ht16, csr_src, gbuf,
                                                starts, counts, edgew[l], hA, n);
  }

  mlp2_kernel<<<(n + 63) / 64, 256, 0, stream>>>(hA, tbuf, l1W, l1b, l2W, l2b,
                                                 (float*)d_out, n);
}

// Round 7
// 723.401 us; speedup vs baseline: 2.2861x; 1.2516x over previous
//
#include <hip/hip_runtime.h>
#include <hip/hip_fp16.h>
#include <math.h>

// ---------------------------------------------------------------------------
// DeepECCNet: 3-layer gated graph conv + t-gate + MLP head.
// v7: tnet/mlp replaced by one MFMA head kernel (16 nodes x 64 cols/wave,
//     W pre-swizzled to B-frag order in 16 KB LDS, fused relu->dot->sigmoid
//     epilogue with 16-lane shfl_xor reduce). v6's vector heads were
//     latency-bound at 122 us each (VALUBusy 35%, occ 33%).
// Conv GEMM: MFMA 16x16x32_f16 (v6). Aggregation: fp16-row gather (v5).
// ---------------------------------------------------------------------------

typedef _Float16 f16x8 __attribute__((ext_vector_type(8)));
typedef float f32x4 __attribute__((ext_vector_type(4)));

__device__ __forceinline__ float sigmoidf_(float v) { return 1.f / (1.f + expf(-v)); }

__global__ void sentinel_kernel(float* __restrict__ out, int n, float val) {
  int i = blockIdx.x * 256 + threadIdx.x;
  if (i < n) out[i] = val;
}

__global__ void zero_kernel(int* __restrict__ p, int n) {
  int i = blockIdx.x * 256 + threadIdx.x;
  if (i < n) p[i] = 0;
}

// ---- edge-index dtype hedge: int64 has all-zero hi (odd) words -------------
__global__ void detect_kernel(const int* __restrict__ ei, int* __restrict__ flag) {
  if (threadIdx.x == 0 && blockIdx.x == 0) {
    int all0 = 1;
    for (int i = 1; i < 512; i += 2) {
      if (ei[i] != 0) { all0 = 0; break; }
    }
    *flag = all0;
  }
}

__global__ void cvt_kernel(const int* __restrict__ ei, int E, const int* __restrict__ flag,
                           int* __restrict__ src32, int* __restrict__ tgt32) {
  int e = blockIdx.x * blockDim.x + threadIdx.x;
  if (e >= E) return;
  if (*flag) {
    const long long* e64 = (const long long*)ei;
    src32[e] = (int)e64[e];
    tgt32[e] = (int)e64[(size_t)E + e];
  } else {
    src32[e] = ei[e];
    tgt32[e] = ei[(size_t)E + e];
  }
}

// ---- CSR build (all index uses bounds-guarded) -----------------------------
__global__ void count_kernel(const int* __restrict__ tgt, int E, int n,
                             int* __restrict__ counts) {
  int e = blockIdx.x * blockDim.x + threadIdx.x;
  if (e < E) {
    unsigned t = (unsigned)tgt[e];
    if (t < (unsigned)n) atomicAdd(&counts[t], 1);
  }
}

__global__ void scan1_kernel(const int* __restrict__ counts, int n,
                             int* __restrict__ starts, int* __restrict__ bsums) {
  __shared__ int tmp[256];
  int i = blockIdx.x * 256 + threadIdx.x;
  int v = (i < n) ? counts[i] : 0;
  tmp[threadIdx.x] = v;
  __syncthreads();
  for (int off = 1; off < 256; off <<= 1) {
    int t = (threadIdx.x >= (unsigned)off) ? tmp[threadIdx.x - off] : 0;
    __syncthreads();
    tmp[threadIdx.x] += t;
    __syncthreads();
  }
  if (i < n) starts[i] = tmp[threadIdx.x] - v;  // exclusive
  if (threadIdx.x == 255) bsums[blockIdx.x] = tmp[255];
}

__global__ void scan2_kernel(int* __restrict__ bsums, int nb) {
  __shared__ int tmp[512];
  int v = (threadIdx.x < (unsigned)nb) ? bsums[threadIdx.x] : 0;
  tmp[threadIdx.x] = v;
  __syncthreads();
  for (int off = 1; off < 512; off <<= 1) {
    int t = (threadIdx.x >= (unsigned)off) ? tmp[threadIdx.x - off] : 0;
    __syncthreads();
    tmp[threadIdx.x] += t;
    __syncthreads();
  }
  if (threadIdx.x < (unsigned)nb) bsums[threadIdx.x] = tmp[threadIdx.x] - v;  // exclusive
}

__global__ void scan3_kernel(int* __restrict__ starts, const int* __restrict__ bsums,
                             int n, int* __restrict__ cursor) {
  int i = blockIdx.x * 256 + threadIdx.x;
  if (i < n) {
    int s = starts[i] + bsums[blockIdx.x];
    starts[i] = s;
    cursor[i] = s;
  }
}

__global__ void fill_kernel(const int* __restrict__ src, const int* __restrict__ tgt,
                            const float* __restrict__ ea, int E, int n,
                            int* __restrict__ cursor,
                            int* __restrict__ csr_src, float* __restrict__ csr_ea) {
  int e = blockIdx.x * blockDim.x + threadIdx.x;
  if (e < E) {
    unsigned t = (unsigned)tgt[e];
    if (t >= (unsigned)n) return;
    int slot = atomicAdd(&cursor[t], 1);
    if ((unsigned)slot < (unsigned)E) {
      csr_src[slot] = src[e];
      csr_ea[slot] = ea[e];
    }
  }
}

// per-layer gate precompute (keeps expf out of the gather hot loop)
__global__ void gates_kernel(const float* __restrict__ csr_ea, const float* __restrict__ wp,
                             float* __restrict__ g, int E) {
  int e = blockIdx.x * blockDim.x + threadIdx.x;
  if (e < E) g[e] = sigmoidf_(csr_ea[e] * wp[0]);
}

// ---- h0 = x[:, 1:]; x0 = x[:, 0] ------------------------------------------
__global__ void slice_kernel(const float* __restrict__ x, float* __restrict__ h,
                             float* __restrict__ x0, int n) {
  int idx = blockIdx.x * blockDim.x + threadIdx.x;
  if (idx < n * 128) {
    int node = idx >> 7;
    int k = idx & 127;
    h[idx] = x[(size_t)node * 129 + 1 + k];
  }
  if (idx < n) x0[idx] = x[(size_t)idx * 129];
}

// ---- unified MFMA head: out = sigmoid( relu(h@W1[hrow0:hrow0+128] +
//        extra*W1[xrow] + b1) @ w2 + b2 )  — tnet: hrow0=1,xrow=0,extra=x0;
//        mlp: hrow0=0,xrow=128,extra=t.
__global__ __launch_bounds__(256) void head_mfma_kernel(const float* __restrict__ h,
    const float* __restrict__ extra, const float* __restrict__ W1,
    const float* __restrict__ b1, const float* __restrict__ w2,
    const float* __restrict__ b2, float* __restrict__ out, int n,
    int hrow0, int xrow) {
  __shared__ __align__(16) _Float16 sB[4 * 4 * 64 * 8];  // 16 KB, B-frag order
  __shared__ float sWx[64], sB1[64], sW2[64];
  for (int idx = threadIdx.x; idx < 8192; idx += 256) {
    int k = idx >> 6, col = idx & 63;
    float w = W1[(size_t)(hrow0 + k) * 64 + col];
    int ks = k >> 5, quad = (k >> 3) & 3, j = k & 7;
    int nt = col >> 4, cl = col & 15;
    sB[(((ks * 4 + nt) * 64) + quad * 16 + cl) * 8 + j] = (_Float16)w;
  }
  if (threadIdx.x < 64) {
    sWx[threadIdx.x] = W1[(size_t)xrow * 64 + threadIdx.x];
    sB1[threadIdx.x] = b1[threadIdx.x];
    sW2[threadIdx.x] = w2[threadIdx.x];
  }
  __syncthreads();
  int wv = threadIdx.x >> 6, lane = threadIdx.x & 63;
  int quad = lane >> 4, l15 = lane & 15;
  int n0 = (blockIdx.x * 4 + wv) * 16;
  if (n0 >= n) return;
  int node_a = min(n0 + l15, n - 1);
  const float* hrow = h + (size_t)node_a * 128 + quad * 8;

  f32x4 acc[4];
#pragma unroll
  for (int t = 0; t < 4; t++) acc[t] = (f32x4){0.f, 0.f, 0.f, 0.f};
  for (int ks = 0; ks < 4; ks++) {
    float4 a0 = ((const float4*)(hrow + ks * 32))[0];
    float4 a1 = ((const float4*)(hrow + ks * 32))[1];
    f16x8 afrag;
    afrag[0] = (_Float16)a0.x; afrag[1] = (_Float16)a0.y;
    afrag[2] = (_Float16)a0.z; afrag[3] = (_Float16)a0.w;
    afrag[4] = (_Float16)a1.x; afrag[5] = (_Float16)a1.y;
    afrag[6] = (_Float16)a1.z; afrag[7] = (_Float16)a1.w;
    const f16x8* bp = (const f16x8*)sB;
#pragma unroll
    for (int t = 0; t < 4; t++) {
      f16x8 bfrag = bp[(ks * 4 + t) * 64 + lane];
      acc[t] = __builtin_amdgcn_mfma_f32_16x16x32_f16(afrag, bfrag, acc[t], 0, 0, 0);
    }
  }
  float b2v = b2[0];
  float xv[4], part[4] = {0.f, 0.f, 0.f, 0.f};
#pragma unroll
  for (int r = 0; r < 4; r++) xv[r] = extra[min(n0 + quad * 4 + r, n - 1)];
#pragma unroll
  for (int t = 0; t < 4; t++) {
    int col = t * 16 + l15;
    float wx = sWx[col], bb = sB1[col], w2v = sW2[col];
#pragma unroll
    for (int r = 0; r < 4; r++) {
      float u = fmaxf(acc[t][r] + xv[r] * wx + bb, 0.f);
      part[r] += u * w2v;
    }
  }
#pragma unroll
  for (int r = 0; r < 4; r++) {
    float p = part[r];
    p += __shfl_xor(p, 1); p += __shfl_xor(p, 2);
    p += __shfl_xor(p, 4); p += __shfl_xor(p, 8);
    int node = n0 + quad * 4 + r;
    if (l15 == 0 && node < n) out[node] = sigmoidf_(p + b2v);
  }
}

// ---- MFMA GEMM: ht16 = f16(h @ W + b) --------------------------------------
__global__ __launch_bounds__(256) void gemm_mfma_kernel(const float* __restrict__ h,
    const float* __restrict__ Wg, const float* __restrict__ b,
    _Float16* __restrict__ out16, int n) {
  __shared__ __align__(16) _Float16 sB[4 * 8 * 64 * 8];  // 32 KB
  for (int i = threadIdx.x; i < 4096; i += 256) {  // i = float4 index over W
    int k = i >> 5;
    int n4 = (i & 31) * 4;
    float4 w4 = ((const float4*)Wg)[i];
    int ks = k >> 5, quad = (k >> 3) & 3, j = k & 7;
#pragma unroll
    for (int c = 0; c < 4; c++) {
      int col = n4 + c;
      int nt = col >> 4, cl = col & 15;
      sB[(((ks * 8 + nt) * 64) + quad * 16 + cl) * 8 + j] =
          (_Float16)((const float*)&w4)[c];
    }
  }
  __syncthreads();
  int wv = threadIdx.x >> 6, lane = threadIdx.x & 63;
  int quad = lane >> 4, l15 = lane & 15;
  int n0 = (blockIdx.x * 4 + wv) * 16;
  if (n0 >= n) return;
  int node_a = min(n0 + l15, n - 1);
  const float* hrow = h + (size_t)node_a * 128 + quad * 8;

  f32x4 acc[8];
#pragma unroll
  for (int t = 0; t < 8; t++) acc[t] = (f32x4){0.f, 0.f, 0.f, 0.f};

  for (int ks = 0; ks < 4; ks++) {
    float4 a0 = ((const float4*)(hrow + ks * 32))[0];
    float4 a1 = ((const float4*)(hrow + ks * 32))[1];
    f16x8 afrag;
    afrag[0] = (_Float16)a0.x; afrag[1] = (_Float16)a0.y;
    afrag[2] = (_Float16)a0.z; afrag[3] = (_Float16)a0.w;
    afrag[4] = (_Float16)a1.x; afrag[5] = (_Float16)a1.y;
    afrag[6] = (_Float16)a1.z; afrag[7] = (_Float16)a1.w;
    const f16x8* bp = (const f16x8*)(sB + ks * 8 * 64 * 8);
#pragma unroll
    for (int t = 0; t < 8; t++) {
      f16x8 bfrag = bp[t * 64 + lane];
      acc[t] = __builtin_amdgcn_mfma_f32_16x16x32_f16(afrag, bfrag, acc[t], 0, 0, 0);
    }
  }
#pragma unroll
  for (int t = 0; t < 8; t++) {
    float bias = b[t * 16 + l15];
#pragma unroll
    for (int r = 0; r < 4; r++) {
      int node = n0 + quad * 4 + r;
      if (node < n)
        out16[(size_t)node * 128 + t * 16 + l15] = (_Float16)(acc[t][r] + bias);
    }
  }
}

// ---- aggregation over fp16 rows, edge loop unrolled x4 ---------------------
__global__ __launch_bounds__(256) void agg_kernel(const __half2* __restrict__ ht,
    const int* __restrict__ csr_src, const float* __restrict__ gates,
    const int* __restrict__ starts, const int* __restrict__ counts,
    const float* __restrict__ wp, float* __restrict__ hout, int n) {
  int wv = threadIdx.x >> 6, lane = threadIdx.x & 63;
  int node = blockIdx.x * 4 + wv;
  if (node >= n) return;
  int s = starts[node], c = counts[node];
  float gs = sigmoidf_(wp[0]);
  float2 v0 = __half22float2(ht[(size_t)node * 64 + lane]);
  float ax = gs * v0.x, ay = gs * v0.y;
  float bx = 0.f, by = 0.f;
  int j = 0;
  for (; j + 4 <= c; j += 4) {
    int sn0 = csr_src[s + j],     sn1 = csr_src[s + j + 1];
    int sn2 = csr_src[s + j + 2], sn3 = csr_src[s + j + 3];
    float g0 = gates[s + j],     g1 = gates[s + j + 1];
    float g2 = gates[s + j + 2], g3 = gates[s + j + 3];
    sn0 = min(max(sn0, 0), n - 1); sn1 = min(max(sn1, 0), n - 1);
    sn2 = min(max(sn2, 0), n - 1); sn3 = min(max(sn3, 0), n - 1);
    float2 f0 = __half22float2(ht[(size_t)sn0 * 64 + lane]);
    float2 f1 = __half22float2(ht[(size_t)sn1 * 64 + lane]);
    float2 f2 = __half22float2(ht[(size_t)sn2 * 64 + lane]);
    float2 f3 = __half22float2(ht[(size_t)sn3 * 64 + lane]);
    ax += g0 * f0.x; ay += g0 * f0.y;
    bx += g1 * f1.x; by += g1 * f1.y;
    ax += g2 * f2.x; ay += g2 * f2.y;
    bx += g3 * f3.x; by += g3 * f3.y;
  }
  for (; j < c; j++) {
    int sn = min(max(csr_src[s + j], 0), n - 1);
    float g = gates[s + j];
    float2 f = __half22float2(ht[(size_t)sn * 64 + lane]);
    ax += g * f.x; ay += g * f.y;
  }
  ax += bx; ay += by;
  float inv = 1.f / (float)(c + 1);
  ax = fmaxf(ax * inv, 0.f);
  ay = fmaxf(ay * inv, 0.f);
  ((float2*)(hout + (size_t)node * 128))[lane] = make_float2(ax, ay);
}

// ---------------------------------------------------------------------------
extern "C" void kernel_launch(void* const* d_in, const int* in_sizes, int n_in,
                              void* d_out, int out_size, void* d_ws, size_t ws_size,
                              hipStream_t stream) {
  int ob = (out_size + 255) / 256;

  const float *x, *ea, *l1W, *l1b, *l2W, *l2b, *t1W, *t1b, *t2W, *t2b;
  const float *convW[3], *convb[3], *edgew[3];
  const int* ei;

  if (n_in == 20) {          // tuples flattened to separate entries
    x = (const float*)d_in[0]; ei = (const int*)d_in[1]; ea = (const float*)d_in[2];
    for (int l = 0; l < 3; l++) {
      convW[l] = (const float*)d_in[3 + l];
      convb[l] = (const float*)d_in[6 + l];
      edgew[l] = (const float*)d_in[9 + l];
    }
    l1W = (const float*)d_in[12]; l1b = (const float*)d_in[13];
    l2W = (const float*)d_in[14]; l2b = (const float*)d_in[15];
    t1W = (const float*)d_in[16]; t1b = (const float*)d_in[17];
    t2W = (const float*)d_in[18]; t2b = (const float*)d_in[19];
  } else if (n_in == 14) {   // each tuple is ONE concatenated buffer
    x = (const float*)d_in[0]; ei = (const int*)d_in[1]; ea = (const float*)d_in[2];
    const float* cw = (const float*)d_in[3];
    const float* cb = (const float*)d_in[4];
    const float* ew = (const float*)d_in[5];
    for (int l = 0; l < 3; l++) {
      convW[l] = cw + (size_t)l * 128 * 128;
      convb[l] = cb + (size_t)l * 128;
      edgew[l] = ew + l;
    }
    l1W = (const float*)d_in[6];  l1b = (const float*)d_in[7];
    l2W = (const float*)d_in[8];  l2b = (const float*)d_in[9];
    t1W = (const float*)d_in[10]; t1b = (const float*)d_in[11];
    t2W = (const float*)d_in[12]; t2b = (const float*)d_in[13];
  } else {
    sentinel_kernel<<<ob, 256, 0, stream>>>((float*)d_out, out_size,
                                            900.0f + (float)n_in);
    return;
  }

  int n = in_sizes[0] / 129;   // 100000
  int E = in_sizes[2];         // 1600000

  char* ws = (char*)d_ws;
  size_t off = 0;
  auto take = [&](size_t bytes) -> void* {
    void* p = ws + off;
    off = (off + bytes + 255) & ~(size_t)255;
    return p;
  };
  int*      flag    = (int*)take(256);
  int*      counts  = (int*)take((size_t)n * 4);
  int*      starts  = (int*)take((size_t)n * 4);
  int*      cursor  = (int*)take((size_t)n * 4);
  int*      bsums   = (int*)take(512 * 4);
  float*    tbuf    = (float*)take((size_t)n * 4);
  float*    x0buf   = (float*)take((size_t)n * 4);
  int*      csr_src = (int*)take((size_t)E * 4);
  float*    csr_ea  = (float*)take((size_t)E * 4);
  float*    gbuf    = (float*)take((size_t)E * 4);
  float*    hA      = (float*)take((size_t)n * 128 * 4);
  _Float16* ht16    = (_Float16*)take((size_t)n * 128 * 2);  // 25.6 MB
  // transient src32/tgt32 alias into ht16 (dead before first GEMM writes it)
  int* src32 = (int*)ht16;
  int* tgt32 = src32 + E;   // 2*E*4 = 12.8 MB <= 25.6 MB

  if (off > ws_size) {
    sentinel_kernel<<<ob, 256, 0, stream>>>((float*)d_out, out_size,
                                            1000.0f + (float)(ws_size >> 20));
    return;
  }

  int eb = (E + 255) / 256;
  int nb = (n + 255) / 256;  // 391 <= 512 (scan2 capacity)

  detect_kernel<<<1, 64, 0, stream>>>(ei, flag);
  cvt_kernel<<<eb, 256, 0, stream>>>(ei, E, flag, src32, tgt32);

  zero_kernel<<<nb, 256, 0, stream>>>(counts, n);
  count_kernel<<<eb, 256, 0, stream>>>(tgt32, E, n, counts);
  scan1_kernel<<<nb, 256, 0, stream>>>(counts, n, starts, bsums);
  scan2_kernel<<<1, 512, 0, stream>>>(bsums, nb);
  scan3_kernel<<<nb, 256, 0, stream>>>(starts, bsums, n, cursor);
  fill_kernel<<<eb, 256, 0, stream>>>(src32, tgt32, ea, E, n, cursor, csr_src, csr_ea);

  int sb = (int)(((size_t)n * 128 + 255) / 256);
  slice_kernel<<<sb, 256, 0, stream>>>(x, hA, x0buf, n);
  // tnet: W1=t1W (129x64), h-rows 1..128, extra=x0 via row 0
  head_mfma_kernel<<<(n + 63) / 64, 256, 0, stream>>>(hA, x0buf, t1W, t1b, t2W, t2b,
                                                      tbuf, n, 1, 0);

  for (int l = 0; l < 3; l++) {
    gemm_mfma_kernel<<<(n + 63) / 64, 256, 0, stream>>>(hA, convW[l], convb[l], ht16, n);
    gates_kernel<<<eb, 256, 0, stream>>>(csr_ea, edgew[l], gbuf, E);
    agg_kernel<<<(n + 3) / 4, 256, 0, stream>>>((const __half2*)ht16, csr_src, gbuf,
                                                starts, counts, edgew[l], hA, n);
  }

  // mlp: W1=l1W (129x64), h-rows 0..127, extra=t via row 128
  head_mfma_kernel<<<(n + 63) / 64, 256, 0, stream>>>(hA, tbuf, l1W, l1b, l2W, l2b,
                                                      (float*)d_out, n, 0, 128);
}